// Round 9
// baseline (644.107 us; speedup 1.0000x reference)
//
#include <hip/hip_runtime.h>
#include <hip/hip_bf16.h>
#include <stdint.h>

// ---------------- problem dims (fixed by setup_inputs) ----------------
#define S_TOK   2048   // tokens (B*S)
#define DMODEL  2048   // D
#define HEXP    512    // H per expert
#define NEXP    32     // E
#define HSH     1024   // shared hidden
#define NPAIR   (S_TOK * 4)   // 8192 (token,expert) pairs, top_k=4
#define MAXTILES 96           // sum ceil(cnt_e/128) <= 8192/128 + 32 = 96

// meta layout (ints)
#define META_NT  0
#define META_TE  1
#define META_TP0 (1 + MAXTILES)
#define META_TM  (1 + 2 * MAXTILES)
#define META_SIZE (1 + 3 * MAXTILES)

typedef short  s16x8 __attribute__((ext_vector_type(8)));
typedef __bf16 b16x8 __attribute__((ext_vector_type(8)));
typedef float  f32x4 __attribute__((ext_vector_type(4)));

__device__ __forceinline__ f32x4 mfma16x16x32(s16x8 a, s16x8 b, f32x4 c) {
    return __builtin_amdgcn_mfma_f32_16x16x32_bf16(
        __builtin_bit_cast(b16x8, a), __builtin_bit_cast(b16x8, b), c, 0, 0, 0);
}

__device__ __forceinline__ unsigned short f2bf(float f) {
    union { float f; unsigned int u; } v; v.f = f;
    unsigned int u = v.u;
    return (unsigned short)((u + 0x7FFFu + ((u >> 16) & 1u)) >> 16);  // RNE
}

__device__ __forceinline__ float bf2f(unsigned short b) {
    union { unsigned int u; float f; } v; v.u = ((unsigned int)b) << 16;
    return v.f;
}

__device__ __forceinline__ s16x8 ldfrag(const unsigned short* p) {
    return *reinterpret_cast<const s16x8*>(p);
}

// ---------------- router: logits, sigmoid, biased top-4, coef softmax ----------------
__global__ __launch_bounds__(256)
void router_kernel(const float* __restrict__ x, const float* __restrict__ gate_w,
                   const float* __restrict__ expert_bias,
                   const float* __restrict__ coef_w, const float* __restrict__ coef_b,
                   int* __restrict__ inds, float* __restrict__ scores,
                   float* __restrict__ coefo)
{
    const int t = blockIdx.x;
    const int tid = threadIdx.x;
    const int lane = tid & 63;
    const int wave = tid >> 6;
    const float* xr = x + (size_t)t * DMODEL;

    float xv[32];
#pragma unroll
    for (int j = 0; j < 32; ++j) xv[j] = xr[lane + 64 * j];

    __shared__ float s_logits[NEXP];
    __shared__ float s_coef[2];

    for (int i = 0; i < 8; ++i) {
        const int e = wave * 8 + i;
        const float* wr = gate_w + (size_t)e * DMODEL;
        float p = 0.f;
#pragma unroll
        for (int j = 0; j < 32; ++j) p += xv[j] * wr[lane + 64 * j];
#pragma unroll
        for (int o = 32; o > 0; o >>= 1) p += __shfl_xor(p, o);
        if (lane == 0) s_logits[e] = p;
    }
    if (wave == 0) {
        for (int c = 0; c < 2; ++c) {
            const float* wr = coef_w + (size_t)c * DMODEL;
            float p = 0.f;
#pragma unroll
            for (int j = 0; j < 32; ++j) p += xv[j] * wr[lane + 64 * j];
#pragma unroll
            for (int o = 32; o > 0; o >>= 1) p += __shfl_xor(p, o);
            if (lane == 0) s_coef[c] = p;
        }
    }
    __syncthreads();
    if (tid == 0) {
        float routing[NEXP], biased[NEXP];
        for (int e = 0; e < NEXP; ++e) {
            const float r = 1.f / (1.f + expf(-s_logits[e]));
            routing[e] = r;
            biased[e] = r + expert_bias[e];
        }
        int sel[4]; float sc[4]; float ssum = 0.f;
        for (int k = 0; k < 4; ++k) {
            int best = 0; float bv = -1e30f;
            for (int e = 0; e < NEXP; ++e)
                if (biased[e] > bv) { bv = biased[e]; best = e; }  // strict > = lax.top_k tie rule
            sel[k] = best; sc[k] = routing[best]; ssum += sc[k];
            biased[best] = -1e30f;
        }
        const float inv = 1.f / (ssum + 1e-20f);
        for (int k = 0; k < 4; ++k) {
            inds[t * 4 + k] = sel[k];
            scores[t * 4 + k] = sc[k] * inv;
        }
        const float l0 = s_coef[0] + coef_b[0];
        const float l1 = s_coef[1] + coef_b[1];
        const float m = fmaxf(l0, l1);
        const float e0 = expf(l0 - m), e1 = expf(l1 - m);
        coefo[t * 2 + 0] = e0 / (e0 + e1);
        coefo[t * 2 + 1] = e1 / (e0 + e1);
    }
}

// ---------------- x: f32 -> bf16 ----------------
__global__ __launch_bounds__(256)
void xcast_kernel(const float* __restrict__ x, unsigned short* __restrict__ xb)
{
    const int i = (blockIdx.x * 256 + threadIdx.x) * 4;
    const float4 v = *reinterpret_cast<const float4*>(x + i);
    ushort4 o;
    o.x = f2bf(v.x); o.y = f2bf(v.y); o.z = f2bf(v.z); o.w = f2bf(v.w);
    *reinterpret_cast<ushort4*>(xb + i) = o;
}

// ---------------- transpose-convert: f32 [K][N] -> bf16 [N][K] (per batch z) ------
__global__ __launch_bounds__(256)
void tconv_kernel(const float* __restrict__ src, unsigned short* __restrict__ dst,
                  const int K, const int N)
{
    __shared__ unsigned short T[64][80];   // [n][k], padded rows (160B)
    const size_t boff = (size_t)blockIdx.z * K * N;
    const float* s = src + boff;
    unsigned short* d = dst + boff;
    const int n0 = blockIdx.x * 64, k0 = blockIdx.y * 64;
    const int tid = threadIdx.x;

    const int n4 = (tid & 15) * 4;
    const int kr = tid >> 4;
#pragma unroll
    for (int i = 0; i < 4; ++i) {
        const int k = kr + i * 16;
        const float4 v = *reinterpret_cast<const float4*>(s + (size_t)(k0 + k) * N + n0 + n4);
        T[n4 + 0][k] = f2bf(v.x);
        T[n4 + 1][k] = f2bf(v.y);
        T[n4 + 2][k] = f2bf(v.z);
        T[n4 + 3][k] = f2bf(v.w);
    }
    __syncthreads();
    const int nw = tid >> 2;
    const int kc = (tid & 3) * 16;
    uint4* o = reinterpret_cast<uint4*>(d + (size_t)(n0 + nw) * K + k0 + kc);
    o[0] = *reinterpret_cast<const uint4*>(&T[nw][kc]);
    o[1] = *reinterpret_cast<const uint4*>(&T[nw][kc + 8]);
}

// ---------------- grouping: per-expert pair lists + tile table + token->pos map ----
__global__ __launch_bounds__(1024)
void group_kernel(const int* __restrict__ inds, const float* __restrict__ scores,
                  int* __restrict__ meta, int* __restrict__ pair_token,
                  float* __restrict__ pair_score, int* __restrict__ tok_pos)
{
    __shared__ int cnt[NEXP];
    __shared__ int off_s[NEXP];
    __shared__ int cur[NEXP];
    const int tid = threadIdx.x;
    if (tid < NEXP) cnt[tid] = 0;
    __syncthreads();
    for (int i = tid; i < NPAIR; i += 1024) atomicAdd(&cnt[inds[i]], 1);
    __syncthreads();
    if (tid == 0) {
        int run = 0, nt = 0;
        for (int e = 0; e < NEXP; ++e) {
            off_s[e] = run;
            const int c = cnt[e];
            for (int m0 = 0; m0 < c; m0 += 128) {
                meta[META_TE + nt] = e;
                meta[META_TP0 + nt] = run + m0;
                meta[META_TM + nt] = (c - m0 < 128) ? (c - m0) : 128;
                ++nt;
            }
            run += c;
        }
        meta[META_NT] = nt;
    }
    __syncthreads();
    if (tid < NEXP) cur[tid] = off_s[tid];
    __syncthreads();
    for (int i = tid; i < NPAIR; i += 1024) {
        const int e = inds[i];
        const int pos = atomicAdd(&cur[e], 1);
        pair_token[pos] = i >> 2;
        pair_score[pos] = scores[i];
        tok_pos[i] = pos;      // token t, slot k -> row in pair-major buffers
    }
}

// ---------------- gate+up GEMM: DIRECT-FRAGMENT, no LDS, no barriers ----------------
// Both operands are [row][k] bf16 with k contiguous, so each lane loads its MFMA
// fragment (16B at row*K + k0 + fq*8) straight from global; L1/L2 serve the reuse.
// BM=128, BN=64 per mat (dual g,u); 4 waves 2x2; wave tile 64m x 32n per mat.
// K-loop: manual unroll-2 with A-prefetch; 8 loads + 16 MFMA per 32-K step.
template <bool GATHER>
__global__ __launch_bounds__(256, 3)
void gateup_kernel(const unsigned short* __restrict__ xb,
                   const unsigned short* __restrict__ Bg_all,
                   const unsigned short* __restrict__ Bu_all,
                   unsigned short* __restrict__ act,
                   const int* __restrict__ meta, const int* __restrict__ pair_token,
                   const int NB)   // act/N stride: 512 (experts) or 1024 (shared)
{
    const int tid = threadIdx.x;
    const int lane = tid & 63;
    const int wave = tid >> 6;
    const int wm = wave >> 1, wn = wave & 1;
    const int fr = lane & 15, fq = lane >> 4;

    int p0, mval;
    const unsigned short *Bg, *Bu;
    if constexpr (GATHER) {
        const int tt = blockIdx.y;
        if (tt >= meta[META_NT]) return;
        const int e = meta[META_TE + tt];
        p0 = meta[META_TP0 + tt];
        mval = meta[META_TM + tt];
        const size_t eoff = (size_t)e * NB * DMODEL;
        Bg = Bg_all + eoff;
        Bu = Bu_all + eoff;
    } else {
        p0 = blockIdx.y * 128;
        mval = 128;
        Bg = Bg_all;
        Bu = Bu_all;
    }
    const int n0 = blockIdx.x * 64;

    // per-lane fragment base pointers (at k-offset fq*8)
    const unsigned short* arow[4];
#pragma unroll
    for (int m = 0; m < 4; ++m) {
        int p = p0 + wm * 64 + m * 16 + fr;
        int tok;
        if constexpr (GATHER) {
            if (p > NPAIR - 1) p = NPAIR - 1;
            tok = pair_token[p];
        } else {
            tok = p;
        }
        arow[m] = xb + (size_t)tok * DMODEL + fq * 8;
    }
    const unsigned short* bgrow[2];
    const unsigned short* burow[2];
#pragma unroll
    for (int n = 0; n < 2; ++n) {
        const int row = n0 + wn * 32 + n * 16 + fr;
        bgrow[n] = Bg + (size_t)row * DMODEL + fq * 8;
        burow[n] = Bu + (size_t)row * DMODEL + fq * 8;
    }

    const f32x4 zero4 = {0.f, 0.f, 0.f, 0.f};
    f32x4 hacc[4][2], uacc[4][2];
#pragma unroll
    for (int m = 0; m < 4; ++m)
#pragma unroll
        for (int n = 0; n < 2; ++n) { hacc[m][n] = zero4; uacc[m][n] = zero4; }

    s16x8 a0[4], a1[4];
    auto LA0 = [&](int k) {
#pragma unroll
        for (int m = 0; m < 4; ++m) a0[m] = ldfrag(arow[m] + k);
    };
    auto LA1 = [&](int k) {
#pragma unroll
        for (int m = 0; m < 4; ++m) a1[m] = ldfrag(arow[m] + k);
    };
    auto STEP = [&](const s16x8* a, int k) {
        const s16x8 g0 = ldfrag(bgrow[0] + k), g1 = ldfrag(bgrow[1] + k);
        const s16x8 u0 = ldfrag(burow[0] + k), u1 = ldfrag(burow[1] + k);
#pragma unroll
        for (int m = 0; m < 4; ++m) {
            hacc[m][0] = mfma16x16x32(a[m], g0, hacc[m][0]);
            hacc[m][1] = mfma16x16x32(a[m], g1, hacc[m][1]);
            uacc[m][0] = mfma16x16x32(a[m], u0, uacc[m][0]);
            uacc[m][1] = mfma16x16x32(a[m], u1, uacc[m][1]);
        }
    };

    LA0(0);
#pragma unroll 1
    for (int k0 = 0; k0 < DMODEL; k0 += 64) {
        LA1(k0 + 32);                       // prefetch next half-step A
        STEP(a0, k0);
        if (k0 + 64 < DMODEL) LA0(k0 + 64); // prefetch next step A
        STEP(a1, k0 + 32);
    }

    // epilogue: act = silu(h)*u -> bf16. C/D frag: col=lane&15, row=fq*4+r
#pragma unroll
    for (int m = 0; m < 4; ++m)
#pragma unroll
        for (int n = 0; n < 2; ++n) {
            const int col = n0 + wn * 32 + n * 16 + fr;
#pragma unroll
            for (int r = 0; r < 4; ++r) {
                const int rt = wm * 64 + m * 16 + fq * 4 + r;
                if (rt < mval) {
                    const float hv = hacc[m][n][r];
                    const float a = hv / (1.f + __expf(-hv)) * uacc[m][n][r];
                    act[(size_t)(p0 + rt) * NB + col] = f2bf(a);
                }
            }
        }
}

// ---------------- down GEMM: DIRECT-FRAGMENT, no LDS. BM=128, BN=128 ----------------
// EXPERT=true : A = act rows (pair-major); epilogue writes y_pair bf16 (score applied).
// EXPERT=false: A = shared act; epilogue gathers token's 4 y_pair rows:
//               out = (sum y)*c0 + shared*c1  (no atomics anywhere).
template <bool EXPERT, int KA>
__global__ __launch_bounds__(256, 3)
void down_kernel(const unsigned short* __restrict__ act,
                 const unsigned short* __restrict__ Bd_all,
                 float* __restrict__ out, unsigned short* __restrict__ ypair,
                 const int* __restrict__ meta, const int* __restrict__ pair_token,
                 const float* __restrict__ pair_score, const float* __restrict__ coef,
                 const int* __restrict__ tok_pos)
{
    const int tid = threadIdx.x;
    const int lane = tid & 63;
    const int wave = tid >> 6;
    const int wm = wave >> 1, wn = wave & 1;
    const int fr = lane & 15, fq = lane >> 4;

    int p0, mval;
    const unsigned short* Bd;
    if constexpr (EXPERT) {
        const int tt = blockIdx.y;
        if (tt >= meta[META_NT]) return;
        const int e = meta[META_TE + tt];
        p0 = meta[META_TP0 + tt];
        mval = meta[META_TM + tt];
        Bd = Bd_all + (size_t)e * DMODEL * KA;
    } else {
        p0 = blockIdx.y * 128;
        mval = 128;
        Bd = Bd_all;
    }
    const int n0 = blockIdx.x * 128;

    const unsigned short* arow[4];
#pragma unroll
    for (int m = 0; m < 4; ++m) {
        int p = p0 + wm * 64 + m * 16 + fr;
        if constexpr (EXPERT) { if (p > NPAIR - 1) p = NPAIR - 1; }
        arow[m] = act + (size_t)p * KA + fq * 8;
    }
    const unsigned short* brow[4];
#pragma unroll
    for (int n = 0; n < 4; ++n) {
        const int row = n0 + wn * 64 + n * 16 + fr;
        brow[n] = Bd + (size_t)row * KA + fq * 8;
    }

    const f32x4 zero4 = {0.f, 0.f, 0.f, 0.f};
    f32x4 acc[4][4];
#pragma unroll
    for (int m = 0; m < 4; ++m)
#pragma unroll
        for (int n = 0; n < 4; ++n) acc[m][n] = zero4;

    s16x8 a0[4], a1[4];
    auto LA0 = [&](int k) {
#pragma unroll
        for (int m = 0; m < 4; ++m) a0[m] = ldfrag(arow[m] + k);
    };
    auto LA1 = [&](int k) {
#pragma unroll
        for (int m = 0; m < 4; ++m) a1[m] = ldfrag(arow[m] + k);
    };
    auto STEP = [&](const s16x8* a, int k) {
        s16x8 bf[4];
#pragma unroll
        for (int n = 0; n < 4; ++n) bf[n] = ldfrag(brow[n] + k);
#pragma unroll
        for (int m = 0; m < 4; ++m)
#pragma unroll
            for (int n = 0; n < 4; ++n)
                acc[m][n] = mfma16x16x32(a[m], bf[n], acc[m][n]);
    };

    LA0(0);
#pragma unroll 1
    for (int k0 = 0; k0 < KA; k0 += 64) {
        LA1(k0 + 32);
        STEP(a0, k0);
        if (k0 + 64 < KA) LA0(k0 + 64);
        STEP(a1, k0 + 32);
    }

#pragma unroll
    for (int m = 0; m < 4; ++m)
#pragma unroll
        for (int n = 0; n < 4; ++n) {
            const int col = n0 + wn * 64 + n * 16 + fr;
#pragma unroll
            for (int r = 0; r < 4; ++r) {
                const int rt = wm * 64 + m * 16 + fq * 4 + r;
                if (rt < mval) {
                    if constexpr (EXPERT) {
                        const int p = p0 + rt;
                        const float s = pair_score[p];
                        ypair[(size_t)p * DMODEL + col] = f2bf(acc[m][n][r] * s);
                    } else {
                        const int row = p0 + rt;     // token
                        float y4 = 0.f;
#pragma unroll
                        for (int k = 0; k < 4; ++k) {
                            const int pos = tok_pos[row * 4 + k];
                            y4 += bf2f(ypair[(size_t)pos * DMODEL + col]);
                        }
                        const float c0 = coef[row * 2 + 0];
                        const float c1 = coef[row * 2 + 1];
                        out[(size_t)row * DMODEL + col] = y4 * c0 + acc[m][n][r] * c1;
                    }
                }
            }
        }
}

// ---------------- launch ----------------
extern "C" void kernel_launch(void* const* d_in, const int* in_sizes, int n_in,
                              void* d_out, int out_size, void* d_ws, size_t ws_size,
                              hipStream_t stream)
{
    const float* x           = (const float*)d_in[0];
    const float* gate_w      = (const float*)d_in[1];
    const float* expert_bias = (const float*)d_in[2];
    const float* wg          = (const float*)d_in[3];
    const float* wu          = (const float*)d_in[4];
    const float* wd          = (const float*)d_in[5];
    const float* sg          = (const float*)d_in[6];
    const float* su          = (const float*)d_in[7];
    const float* sd          = (const float*)d_in[8];
    const float* coef_w      = (const float*)d_in[9];
    const float* coef_b      = (const float*)d_in[10];
    float* out = (float*)d_out;

    char* ws = (char*)d_ws;
    size_t off = 0;
    auto take = [&](size_t bytes) {
        char* p = ws + off;
        off = (off + bytes + 255) & ~(size_t)255;
        return p;
    };
    int*   inds     = (int*)  take((size_t)S_TOK * 4 * sizeof(int));
    float* scores   = (float*)take((size_t)S_TOK * 4 * sizeof(float));
    float* coefp    = (float*)take((size_t)S_TOK * 2 * sizeof(float));
    int*   meta     = (int*)  take((size_t)META_SIZE * sizeof(int));
    int*   pair_tok = (int*)  take((size_t)NPAIR * sizeof(int));
    float* pair_sc  = (float*)take((size_t)NPAIR * sizeof(float));
    int*   tok_pos  = (int*)  take((size_t)NPAIR * sizeof(int));
    unsigned short* xb    = (unsigned short*)take((size_t)S_TOK * DMODEL * 2);
    unsigned short* act   = (unsigned short*)take((size_t)NPAIR * HEXP * 2);
    unsigned short* shact = (unsigned short*)take((size_t)S_TOK * HSH * 2);
    unsigned short* ypair = (unsigned short*)take((size_t)NPAIR * DMODEL * 2);  // 33.5MB
    unsigned short* sgb   = (unsigned short*)take((size_t)HSH * DMODEL * 2);    // [HS][D]
    unsigned short* sub_  = (unsigned short*)take((size_t)HSH * DMODEL * 2);    // [HS][D]
    unsigned short* sdb   = (unsigned short*)take((size_t)DMODEL * HSH * 2);    // [D][HS]
    unsigned short* W1    = (unsigned short*)take((size_t)NEXP * DMODEL * HEXP * 2); // 64MB
    unsigned short* W2    = (unsigned short*)take((size_t)NEXP * DMODEL * HEXP * 2); // 64MB
    (void)ws_size; (void)in_sizes; (void)n_in; (void)out_size;

    router_kernel<<<S_TOK, 256, 0, stream>>>(x, gate_w, expert_bias, coef_w, coef_b,
                                             inds, scores, coefp);
    xcast_kernel<<<(S_TOK * DMODEL / 4) / 256, 256, 0, stream>>>(x, xb);
    group_kernel<<<1, 1024, 0, stream>>>(inds, scores, meta, pair_tok, pair_sc, tok_pos);

    // transpose-convert weights: f32 [K][N] -> bf16 [N][K]
    tconv_kernel<<<dim3(HSH / 64, DMODEL / 64, 1), 256, 0, stream>>>(sg, sgb, DMODEL, HSH);
    tconv_kernel<<<dim3(HSH / 64, DMODEL / 64, 1), 256, 0, stream>>>(su, sub_, DMODEL, HSH);
    tconv_kernel<<<dim3(DMODEL / 64, HSH / 64, 1), 256, 0, stream>>>(sd, sdb, HSH, DMODEL);
    tconv_kernel<<<dim3(HEXP / 64, DMODEL / 64, NEXP), 256, 0, stream>>>(wg, W1, DMODEL, HEXP);
    tconv_kernel<<<dim3(HEXP / 64, DMODEL / 64, NEXP), 256, 0, stream>>>(wu, W2, DMODEL, HEXP);

    // expert gate+up (+SwiGLU)
    gateup_kernel<true><<<dim3(HEXP / 64, MAXTILES), 256, 0, stream>>>(
        xb, W1, W2, act, meta, pair_tok, HEXP);
    // shared gate+up: N=1024, M=2048
    gateup_kernel<false><<<dim3(HSH / 64, S_TOK / 128), 256, 0, stream>>>(
        xb, sgb, sub_, shact, nullptr, nullptr, HSH);

    // wd -> bf16 [E][D][H] into W1 (wgb dead after expert gateup)
    tconv_kernel<<<dim3(DMODEL / 64, HEXP / 64, NEXP), 256, 0, stream>>>(wd, W1, HEXP, DMODEL);

    // expert down: y_pair[p][D] = (act_p . wd_e) * score_p   (plain bf16 stores)
    down_kernel<true, HEXP><<<dim3(DMODEL / 128, MAXTILES), 256, 0, stream>>>(
        act, W1, out, ypair, meta, pair_tok, pair_sc, nullptr, tok_pos);
    // shared down + gather 4 y_pair rows + coef mix -> out (each element written once)
    down_kernel<false, HSH><<<dim3(DMODEL / 128, S_TOK / 128), 256, 0, stream>>>(
        shact, sdb, out, ypair, nullptr, nullptr, nullptr, coefp, tok_pos);
}

// Round 10
// 399.924 us; speedup vs baseline: 1.6106x; 1.6106x over previous
//
#include <hip/hip_runtime.h>
#include <hip/hip_bf16.h>
#include <stdint.h>

// ---------------- problem dims (fixed by setup_inputs) ----------------
#define S_TOK   2048   // tokens (B*S)
#define DMODEL  2048   // D
#define HEXP    512    // H per expert
#define NEXP    32     // E
#define HSH     1024   // shared hidden
#define NPAIR   (S_TOK * 4)   // 8192 (token,expert) pairs, top_k=4
#define MAXTILES 160          // sum ceil(cnt_e/64) <= 8192/64 + 32 = 160

// meta layout (ints)
#define META_NT  0
#define META_TE  1
#define META_TP0 (1 + MAXTILES)
#define META_TM  (1 + 2 * MAXTILES)
#define META_SIZE (1 + 3 * MAXTILES)

typedef short  s16x8 __attribute__((ext_vector_type(8)));
typedef __bf16 b16x8 __attribute__((ext_vector_type(8)));
typedef float  f32x4 __attribute__((ext_vector_type(4)));

__device__ __forceinline__ f32x4 mfma16x16x32(s16x8 a, s16x8 b, f32x4 c) {
    return __builtin_amdgcn_mfma_f32_16x16x32_bf16(
        __builtin_bit_cast(b16x8, a), __builtin_bit_cast(b16x8, b), c, 0, 0, 0);
}

__device__ __forceinline__ unsigned short f2bf(float f) {
    union { float f; unsigned int u; } v; v.f = f;
    unsigned int u = v.u;
    return (unsigned short)((u + 0x7FFFu + ((u >> 16) & 1u)) >> 16);  // RNE
}

__device__ __forceinline__ float bf2f(unsigned short b) {
    union { unsigned int u; float f; } v; v.u = ((unsigned int)b) << 16;
    return v.f;
}

// async global->LDS, 16B per lane. LDS dest is wave-uniform base + lane*16.
__device__ __forceinline__ void gload16(const unsigned short* g, unsigned short* l) {
    __builtin_amdgcn_global_load_lds(
        (const __attribute__((address_space(1))) void*)(uintptr_t)g,
        (__attribute__((address_space(3))) void*)(uintptr_t)l, 16, 0, 0);
}

// ---------------- router: logits, sigmoid, biased top-4, coef softmax ----------------
__global__ __launch_bounds__(256)
void router_kernel(const float* __restrict__ x, const float* __restrict__ gate_w,
                   const float* __restrict__ expert_bias,
                   const float* __restrict__ coef_w, const float* __restrict__ coef_b,
                   int* __restrict__ inds, float* __restrict__ scores,
                   float* __restrict__ coefo)
{
    const int t = blockIdx.x;
    const int tid = threadIdx.x;
    const int lane = tid & 63;
    const int wave = tid >> 6;
    const float* xr = x + (size_t)t * DMODEL;

    float xv[32];
#pragma unroll
    for (int j = 0; j < 32; ++j) xv[j] = xr[lane + 64 * j];

    __shared__ float s_logits[NEXP];
    __shared__ float s_coef[2];

    for (int i = 0; i < 8; ++i) {
        const int e = wave * 8 + i;
        const float* wr = gate_w + (size_t)e * DMODEL;
        float p = 0.f;
#pragma unroll
        for (int j = 0; j < 32; ++j) p += xv[j] * wr[lane + 64 * j];
#pragma unroll
        for (int o = 32; o > 0; o >>= 1) p += __shfl_xor(p, o);
        if (lane == 0) s_logits[e] = p;
    }
    if (wave == 0) {
        for (int c = 0; c < 2; ++c) {
            const float* wr = coef_w + (size_t)c * DMODEL;
            float p = 0.f;
#pragma unroll
            for (int j = 0; j < 32; ++j) p += xv[j] * wr[lane + 64 * j];
#pragma unroll
            for (int o = 32; o > 0; o >>= 1) p += __shfl_xor(p, o);
            if (lane == 0) s_coef[c] = p;
        }
    }
    __syncthreads();
    if (tid == 0) {
        float routing[NEXP], biased[NEXP];
        for (int e = 0; e < NEXP; ++e) {
            const float r = 1.f / (1.f + expf(-s_logits[e]));
            routing[e] = r;
            biased[e] = r + expert_bias[e];
        }
        int sel[4]; float sc[4]; float ssum = 0.f;
        for (int k = 0; k < 4; ++k) {
            int best = 0; float bv = -1e30f;
            for (int e = 0; e < NEXP; ++e)
                if (biased[e] > bv) { bv = biased[e]; best = e; }  // strict > = lax.top_k tie rule
            sel[k] = best; sc[k] = routing[best]; ssum += sc[k];
            biased[best] = -1e30f;
        }
        const float inv = 1.f / (ssum + 1e-20f);
        for (int k = 0; k < 4; ++k) {
            inds[t * 4 + k] = sel[k];
            scores[t * 4 + k] = sc[k] * inv;
        }
        const float l0 = s_coef[0] + coef_b[0];
        const float l1 = s_coef[1] + coef_b[1];
        const float m = fmaxf(l0, l1);
        const float e0 = expf(l0 - m), e1 = expf(l1 - m);
        coefo[t * 2 + 0] = e0 / (e0 + e1);
        coefo[t * 2 + 1] = e1 / (e0 + e1);
    }
}

// ---------------- x: f32 -> bf16 ----------------
__global__ __launch_bounds__(256)
void xcast_kernel(const float* __restrict__ x, unsigned short* __restrict__ xb)
{
    const int i = (blockIdx.x * 256 + threadIdx.x) * 4;
    const float4 v = *reinterpret_cast<const float4*>(x + i);
    ushort4 o;
    o.x = f2bf(v.x); o.y = f2bf(v.y); o.z = f2bf(v.z); o.w = f2bf(v.w);
    *reinterpret_cast<ushort4*>(xb + i) = o;
}

// ---------------- transpose-convert: f32 [K][N] -> bf16 [N][K] (per batch z) ------
__global__ __launch_bounds__(256)
void tconv_kernel(const float* __restrict__ src, unsigned short* __restrict__ dst,
                  const int K, const int N)
{
    __shared__ unsigned short T[64][80];   // [n][k], padded rows (160B)
    const size_t boff = (size_t)blockIdx.z * K * N;
    const float* s = src + boff;
    unsigned short* d = dst + boff;
    const int n0 = blockIdx.x * 64, k0 = blockIdx.y * 64;
    const int tid = threadIdx.x;

    const int n4 = (tid & 15) * 4;
    const int kr = tid >> 4;
#pragma unroll
    for (int i = 0; i < 4; ++i) {
        const int k = kr + i * 16;
        const float4 v = *reinterpret_cast<const float4*>(s + (size_t)(k0 + k) * N + n0 + n4);
        T[n4 + 0][k] = f2bf(v.x);
        T[n4 + 1][k] = f2bf(v.y);
        T[n4 + 2][k] = f2bf(v.z);
        T[n4 + 3][k] = f2bf(v.w);
    }
    __syncthreads();
    const int nw = tid >> 2;
    const int kc = (tid & 3) * 16;
    uint4* o = reinterpret_cast<uint4*>(d + (size_t)(n0 + nw) * K + k0 + kc);
    o[0] = *reinterpret_cast<const uint4*>(&T[nw][kc]);
    o[1] = *reinterpret_cast<const uint4*>(&T[nw][kc + 8]);
}

// ---------------- grouping: per-expert pair lists + 64-row tile table + pos map ----
__global__ __launch_bounds__(1024)
void group_kernel(const int* __restrict__ inds, const float* __restrict__ scores,
                  int* __restrict__ meta, int* __restrict__ pair_token,
                  float* __restrict__ pair_score, int* __restrict__ tok_pos)
{
    __shared__ int cnt[NEXP];
    __shared__ int off_s[NEXP];
    __shared__ int cur[NEXP];
    const int tid = threadIdx.x;
    if (tid < NEXP) cnt[tid] = 0;
    __syncthreads();
    for (int i = tid; i < NPAIR; i += 1024) atomicAdd(&cnt[inds[i]], 1);
    __syncthreads();
    if (tid == 0) {
        int run = 0, nt = 0;
        for (int e = 0; e < NEXP; ++e) {
            off_s[e] = run;
            const int c = cnt[e];
            for (int m0 = 0; m0 < c; m0 += 64) {
                meta[META_TE + nt] = e;
                meta[META_TP0 + nt] = run + m0;
                meta[META_TM + nt] = (c - m0 < 64) ? (c - m0) : 64;
                ++nt;
            }
            run += c;
        }
        meta[META_NT] = nt;
    }
    __syncthreads();
    if (tid < NEXP) cur[tid] = off_s[tid];
    __syncthreads();
    for (int i = tid; i < NPAIR; i += 1024) {
        const int e = inds[i];
        const int pos = atomicAdd(&cur[e], 1);
        pair_token[pos] = i >> 2;
        pair_score[pos] = scores[i];
        tok_pos[i] = pos;      // token t, slot k -> row in pair-major buffers
    }
}

// ---------------- gate+up GEMM (bf16 weights, pre-transposed), fused SwiGLU -------
// BM=64, BK=32, dual-B (g,u) 64 cols each; 4 waves 2x2, wave tile 32m x 32n per mat.
// global_load_lds staging (3 gloads/thread), double-buffered LDS, one barrier/K-step.
// Small tile -> 2-3x more blocks than BM=128: fills the grid-limited occupancy that
// capped r7/r8 (2.15 blocks/CU measured).
template <bool GATHER>
__global__ __launch_bounds__(256, 4)
void gateup_kernel(const unsigned short* __restrict__ xb,
                   const unsigned short* __restrict__ Bg_all,
                   const unsigned short* __restrict__ Bu_all,
                   unsigned short* __restrict__ act,
                   const int* __restrict__ meta, const int* __restrict__ pair_token,
                   const int NB)   // act/N stride: 512 (experts) or 1024 (shared)
{
    constexpr int NT = DMODEL / 32;   // 64 K-steps
    __shared__ unsigned short Al[2][64][32];
    __shared__ unsigned short Bgl[2][64][32];
    __shared__ unsigned short Bul[2][64][32];

    const int tid = threadIdx.x;
    const int lane = tid & 63;
    const int wave = tid >> 6;

    int p0, mval;
    const unsigned short *Bg, *Bu;
    if constexpr (GATHER) {
        const int tt = blockIdx.y;
        if (tt >= meta[META_NT]) return;
        const int e = meta[META_TE + tt];
        p0 = meta[META_TP0 + tt];
        mval = meta[META_TM + tt];
        const size_t eoff = (size_t)e * NB * DMODEL;
        Bg = Bg_all + eoff;
        Bu = Bu_all + eoff;
    } else {
        p0 = blockIdx.y * 64;
        mval = 64;
        Bg = Bg_all;
        Bu = Bu_all;
    }
    const int n0 = blockIdx.x * 64;

    // staging: each wave covers 16 rows (1024B chunk); lane -> row sub, 16B chunk
    const int sub  = lane >> 2;          // 0..15
    const int col8 = (lane & 3) * 8;     // k-offset in shorts
    const int arow = wave * 16 + sub;
    int tok;
    if constexpr (GATHER) {
        int q = p0 + arow; if (q > NPAIR - 1) q = NPAIR - 1;
        tok = pair_token[q];
    } else {
        tok = p0 + arow;
    }
    const unsigned short* asrc = xb + (size_t)tok * DMODEL + col8;
    const unsigned short* gsrc = Bg + (size_t)(n0 + arow) * DMODEL + col8;
    const unsigned short* usrc = Bu + (size_t)(n0 + arow) * DMODEL + col8;

    auto stage = [&](int buf, int k0) {
        gload16(asrc + k0, &Al[buf][wave * 16][0]);
        gload16(gsrc + k0, &Bgl[buf][wave * 16][0]);
        gload16(usrc + k0, &Bul[buf][wave * 16][0]);
    };

    const int wm = wave >> 1, wn = wave & 1;
    const int fr = lane & 15, fq = lane >> 4;

    const f32x4 zero4 = {0.f, 0.f, 0.f, 0.f};
    f32x4 hacc[2][2], uacc[2][2];
#pragma unroll
    for (int m = 0; m < 2; ++m)
#pragma unroll
        for (int n = 0; n < 2; ++n) { hacc[m][n] = zero4; uacc[m][n] = zero4; }

    auto compute = [&](int buf) {
        const int ko = fq * 8;
        s16x8 af[2], bg[2], bu[2];
#pragma unroll
        for (int m = 0; m < 2; ++m)
            af[m] = *reinterpret_cast<const s16x8*>(&Al[buf][wm * 32 + m * 16 + fr][ko]);
#pragma unroll
        for (int n = 0; n < 2; ++n) {
            bg[n] = *reinterpret_cast<const s16x8*>(&Bgl[buf][wn * 32 + n * 16 + fr][ko]);
            bu[n] = *reinterpret_cast<const s16x8*>(&Bul[buf][wn * 32 + n * 16 + fr][ko]);
        }
#pragma unroll
        for (int m = 0; m < 2; ++m)
#pragma unroll
            for (int n = 0; n < 2; ++n) {
                hacc[m][n] = mfma16x16x32(af[m], bg[n], hacc[m][n]);
                uacc[m][n] = mfma16x16x32(af[m], bu[n], uacc[m][n]);
            }
    };

    stage(0, 0);
    __syncthreads();           // drains vmcnt(0): tile 0 ready
#pragma unroll 1
    for (int t = 0; t < NT; ++t) {
        const int cur = t & 1;
        if (t + 1 < NT) stage(cur ^ 1, (t + 1) * 32);  // loads fly under compute
        compute(cur);
        __syncthreads();
    }

    // epilogue: act = silu(h)*u -> bf16. C/D frag: col=lane&15, row=fq*4+r
#pragma unroll
    for (int m = 0; m < 2; ++m)
#pragma unroll
        for (int n = 0; n < 2; ++n) {
            const int col = n0 + wn * 32 + n * 16 + fr;
#pragma unroll
            for (int r = 0; r < 4; ++r) {
                const int rt = wm * 32 + m * 16 + fq * 4 + r;
                if (rt < mval) {
                    const float hv = hacc[m][n][r];
                    const float a = hv / (1.f + __expf(-hv)) * uacc[m][n][r];
                    act[(size_t)(p0 + rt) * NB + col] = f2bf(a);
                }
            }
        }
}

// ---------------- down GEMM: BM=64, BN=64, BK=32, bf16 transposed weights -------
// EXPERT=true : A = act rows (pair-major); epilogue writes y_pair bf16 (score applied).
// EXPERT=false: A = shared act; epilogue gathers token's 4 y_pair rows:
//               out = (sum y)*c0 + shared*c1  (no atomics anywhere).
template <bool EXPERT, int KA>
__global__ __launch_bounds__(256, 4)
void down_kernel(const unsigned short* __restrict__ act,
                 const unsigned short* __restrict__ Bd_all,
                 float* __restrict__ out, unsigned short* __restrict__ ypair,
                 const int* __restrict__ meta, const int* __restrict__ pair_token,
                 const float* __restrict__ pair_score, const float* __restrict__ coef,
                 const int* __restrict__ tok_pos)
{
    constexpr int NT = KA / 32;   // 16 or 32
    __shared__ unsigned short Al[2][64][32];
    __shared__ unsigned short Bl[2][64][32];

    const int tid = threadIdx.x;
    const int lane = tid & 63;
    const int wave = tid >> 6;

    int p0, mval;
    const unsigned short* Bd;
    if constexpr (EXPERT) {
        const int tt = blockIdx.y;
        if (tt >= meta[META_NT]) return;
        const int e = meta[META_TE + tt];
        p0 = meta[META_TP0 + tt];
        mval = meta[META_TM + tt];
        Bd = Bd_all + (size_t)e * DMODEL * KA;
    } else {
        p0 = blockIdx.y * 64;
        mval = 64;
        Bd = Bd_all;
    }
    const int n0 = blockIdx.x * 64;

    const int sub  = lane >> 2;
    const int col8 = (lane & 3) * 8;
    const int arow = wave * 16 + sub;
    int ar = p0 + arow;
    if constexpr (EXPERT) { if (ar > NPAIR - 1) ar = NPAIR - 1; }
    const unsigned short* asrc = act + (size_t)ar * KA + col8;
    const unsigned short* bsrc = Bd + (size_t)(n0 + arow) * KA + col8;

    auto stage = [&](int buf, int k0) {
        gload16(asrc + k0, &Al[buf][wave * 16][0]);
        gload16(bsrc + k0, &Bl[buf][wave * 16][0]);
    };

    const int wm = wave >> 1, wn = wave & 1;
    const int fr = lane & 15, fq = lane >> 4;

    const f32x4 zero4 = {0.f, 0.f, 0.f, 0.f};
    f32x4 acc[2][2];
#pragma unroll
    for (int m = 0; m < 2; ++m)
#pragma unroll
        for (int n = 0; n < 2; ++n) acc[m][n] = zero4;

    auto compute = [&](int buf) {
        const int ko = fq * 8;
        s16x8 af[2], bf[2];
#pragma unroll
        for (int m = 0; m < 2; ++m)
            af[m] = *reinterpret_cast<const s16x8*>(&Al[buf][wm * 32 + m * 16 + fr][ko]);
#pragma unroll
        for (int n = 0; n < 2; ++n)
            bf[n] = *reinterpret_cast<const s16x8*>(&Bl[buf][wn * 32 + n * 16 + fr][ko]);
#pragma unroll
        for (int m = 0; m < 2; ++m)
#pragma unroll
            for (int n = 0; n < 2; ++n)
                acc[m][n] = mfma16x16x32(af[m], bf[n], acc[m][n]);
    };

    stage(0, 0);
    __syncthreads();
#pragma unroll 1
    for (int t = 0; t < NT; ++t) {
        const int cur = t & 1;
        if (t + 1 < NT) stage(cur ^ 1, (t + 1) * 32);
        compute(cur);
        __syncthreads();
    }

#pragma unroll
    for (int m = 0; m < 2; ++m)
#pragma unroll
        for (int n = 0; n < 2; ++n) {
            const int col = n0 + wn * 32 + n * 16 + fr;
#pragma unroll
            for (int r = 0; r < 4; ++r) {
                const int rt = wm * 32 + m * 16 + fq * 4 + r;
                if (rt < mval) {
                    if constexpr (EXPERT) {
                        const int p = p0 + rt;
                        const float s = pair_score[p];
                        ypair[(size_t)p * DMODEL + col] = f2bf(acc[m][n][r] * s);
                    } else {
                        const int row = p0 + rt;     // token
                        float y4 = 0.f;
#pragma unroll
                        for (int k = 0; k < 4; ++k) {
                            const int pos = tok_pos[row * 4 + k];
                            y4 += bf2f(ypair[(size_t)pos * DMODEL + col]);
                        }
                        const float c0 = coef[row * 2 + 0];
                        const float c1 = coef[row * 2 + 1];
                        out[(size_t)row * DMODEL + col] = y4 * c0 + acc[m][n][r] * c1;
                    }
                }
            }
        }
}

// ---------------- launch ----------------
extern "C" void kernel_launch(void* const* d_in, const int* in_sizes, int n_in,
                              void* d_out, int out_size, void* d_ws, size_t ws_size,
                              hipStream_t stream)
{
    const float* x           = (const float*)d_in[0];
    const float* gate_w      = (const float*)d_in[1];
    const float* expert_bias = (const float*)d_in[2];
    const float* wg          = (const float*)d_in[3];
    const float* wu          = (const float*)d_in[4];
    const float* wd          = (const float*)d_in[5];
    const float* sg          = (const float*)d_in[6];
    const float* su          = (const float*)d_in[7];
    const float* sd          = (const float*)d_in[8];
    const float* coef_w      = (const float*)d_in[9];
    const float* coef_b      = (const float*)d_in[10];
    float* out = (float*)d_out;

    char* ws = (char*)d_ws;
    size_t off = 0;
    auto take = [&](size_t bytes) {
        char* p = ws + off;
        off = (off + bytes + 255) & ~(size_t)255;
        return p;
    };
    int*   inds     = (int*)  take((size_t)S_TOK * 4 * sizeof(int));
    float* scores   = (float*)take((size_t)S_TOK * 4 * sizeof(float));
    float* coefp    = (float*)take((size_t)S_TOK * 2 * sizeof(float));
    int*   meta     = (int*)  take((size_t)META_SIZE * sizeof(int));
    int*   pair_tok = (int*)  take((size_t)NPAIR * sizeof(int));
    float* pair_sc  = (float*)take((size_t)NPAIR * sizeof(float));
    int*   tok_pos  = (int*)  take((size_t)NPAIR * sizeof(int));
    unsigned short* xb    = (unsigned short*)take((size_t)S_TOK * DMODEL * 2);
    unsigned short* act   = (unsigned short*)take((size_t)NPAIR * HEXP * 2);
    unsigned short* shact = (unsigned short*)take((size_t)S_TOK * HSH * 2);
    unsigned short* ypair = (unsigned short*)take((size_t)NPAIR * DMODEL * 2);  // 33.5MB
    unsigned short* sgb   = (unsigned short*)take((size_t)HSH * DMODEL * 2);    // [HS][D]
    unsigned short* sub_  = (unsigned short*)take((size_t)HSH * DMODEL * 2);    // [HS][D]
    unsigned short* sdb   = (unsigned short*)take((size_t)DMODEL * HSH * 2);    // [D][HS]
    unsigned short* W1    = (unsigned short*)take((size_t)NEXP * DMODEL * HEXP * 2); // 64MB
    unsigned short* W2    = (unsigned short*)take((size_t)NEXP * DMODEL * HEXP * 2); // 64MB
    (void)ws_size; (void)in_sizes; (void)n_in; (void)out_size;

    router_kernel<<<S_TOK, 256, 0, stream>>>(x, gate_w, expert_bias, coef_w, coef_b,
                                             inds, scores, coefp);
    xcast_kernel<<<(S_TOK * DMODEL / 4) / 256, 256, 0, stream>>>(x, xb);
    group_kernel<<<1, 1024, 0, stream>>>(inds, scores, meta, pair_tok, pair_sc, tok_pos);

    // transpose-convert weights: f32 [K][N] -> bf16 [N][K]
    tconv_kernel<<<dim3(HSH / 64, DMODEL / 64, 1), 256, 0, stream>>>(sg, sgb, DMODEL, HSH);
    tconv_kernel<<<dim3(HSH / 64, DMODEL / 64, 1), 256, 0, stream>>>(su, sub_, DMODEL, HSH);
    tconv_kernel<<<dim3(DMODEL / 64, HSH / 64, 1), 256, 0, stream>>>(sd, sdb, HSH, DMODEL);
    tconv_kernel<<<dim3(HEXP / 64, DMODEL / 64, NEXP), 256, 0, stream>>>(wg, W1, DMODEL, HEXP);
    tconv_kernel<<<dim3(HEXP / 64, DMODEL / 64, NEXP), 256, 0, stream>>>(wu, W2, DMODEL, HEXP);

    // expert gate+up (+SwiGLU): 8 n-tiles x up-to-160 m-tiles (64-row tile table)
    gateup_kernel<true><<<dim3(HEXP / 64, MAXTILES), 256, 0, stream>>>(
        xb, W1, W2, act, meta, pair_tok, HEXP);
    // shared gate+up: N=1024 (16 n-tiles), M=2048 (32 m-tiles)
    gateup_kernel<false><<<dim3(HSH / 64, S_TOK / 64), 256, 0, stream>>>(
        xb, sgb, sub_, shact, nullptr, nullptr, HSH);

    // wd -> bf16 [E][D][H] into W1 (wgb dead after expert gateup)
    tconv_kernel<<<dim3(DMODEL / 64, HEXP / 64, NEXP), 256, 0, stream>>>(wd, W1, HEXP, DMODEL);

    // expert down: y_pair[p][D] = (act_p . wd_e) * score_p   (plain bf16 stores)
    down_kernel<true, HEXP><<<dim3(DMODEL / 64, MAXTILES), 256, 0, stream>>>(
        act, W1, out, ypair, meta, pair_tok, pair_sc, nullptr, tok_pos);
    // shared down + gather 4 y_pair rows + coef mix -> out (each element written once)
    down_kernel<false, HSH><<<dim3(DMODEL / 64, S_TOK / 64), 256, 0, stream>>>(
        shact, sdb, out, ypair, nullptr, nullptr, nullptr, coefp, tok_pos);
}

// Round 11
// 391.990 us; speedup vs baseline: 1.6432x; 1.0202x over previous
//
#include <hip/hip_runtime.h>
#include <hip/hip_bf16.h>
#include <stdint.h>

// ---------------- problem dims (fixed by setup_inputs) ----------------
#define S_TOK   2048   // tokens (B*S)
#define DMODEL  2048   // D
#define HEXP    512    // H per expert
#define NEXP    32     // E
#define HSH     1024   // shared hidden
#define NPAIR   (S_TOK * 4)   // 8192 (token,expert) pairs, top_k=4
#define NT128   96            // sum ceil(cnt_e/128) <= 8192/128 + 32
#define NT64    160           // sum ceil(cnt_e/64)  <= 8192/64  + 32

// meta layout (ints): two tile tables (128-row for gateup_e, 64-row for down_e)
#define M128_NT  0
#define M128_TE  1
#define M128_TP0 (1 + NT128)
#define M128_TM  (1 + 2 * NT128)
#define M64_NT   (1 + 3 * NT128)
#define M64_TE   (M64_NT + 1)
#define M64_TP0  (M64_NT + 1 + NT64)
#define M64_TM   (M64_NT + 1 + 2 * NT64)
#define META_SIZE (M64_NT + 1 + 3 * NT64)

typedef short  s16x8 __attribute__((ext_vector_type(8)));
typedef __bf16 b16x8 __attribute__((ext_vector_type(8)));
typedef float  f32x4 __attribute__((ext_vector_type(4)));

__device__ __forceinline__ f32x4 mfma16x16x32(s16x8 a, s16x8 b, f32x4 c) {
    return __builtin_amdgcn_mfma_f32_16x16x32_bf16(
        __builtin_bit_cast(b16x8, a), __builtin_bit_cast(b16x8, b), c, 0, 0, 0);
}

__device__ __forceinline__ unsigned short f2bf(float f) {
    union { float f; unsigned int u; } v; v.f = f;
    unsigned int u = v.u;
    return (unsigned short)((u + 0x7FFFu + ((u >> 16) & 1u)) >> 16);  // RNE
}

__device__ __forceinline__ float bf2f(unsigned short b) {
    union { unsigned int u; float f; } v; v.u = ((unsigned int)b) << 16;
    return v.f;
}

// async global->LDS, 16B per lane. LDS dest is wave-uniform base + lane*16.
__device__ __forceinline__ void gload16(const unsigned short* g, unsigned short* l) {
    __builtin_amdgcn_global_load_lds(
        (const __attribute__((address_space(1))) void*)(uintptr_t)g,
        (__attribute__((address_space(3))) void*)(uintptr_t)l, 16, 0, 0);
}

// ---------------- router: logits, sigmoid, biased top-4, coef softmax ----------------
__global__ __launch_bounds__(256)
void router_kernel(const float* __restrict__ x, const float* __restrict__ gate_w,
                   const float* __restrict__ expert_bias,
                   const float* __restrict__ coef_w, const float* __restrict__ coef_b,
                   int* __restrict__ inds, float* __restrict__ scores,
                   float* __restrict__ coefo)
{
    const int t = blockIdx.x;
    const int tid = threadIdx.x;
    const int lane = tid & 63;
    const int wave = tid >> 6;
    const float* xr = x + (size_t)t * DMODEL;

    float xv[32];
#pragma unroll
    for (int j = 0; j < 32; ++j) xv[j] = xr[lane + 64 * j];

    __shared__ float s_logits[NEXP];
    __shared__ float s_coef[2];

    for (int i = 0; i < 8; ++i) {
        const int e = wave * 8 + i;
        const float* wr = gate_w + (size_t)e * DMODEL;
        float p = 0.f;
#pragma unroll
        for (int j = 0; j < 32; ++j) p += xv[j] * wr[lane + 64 * j];
#pragma unroll
        for (int o = 32; o > 0; o >>= 1) p += __shfl_xor(p, o);
        if (lane == 0) s_logits[e] = p;
    }
    if (wave == 0) {
        for (int c = 0; c < 2; ++c) {
            const float* wr = coef_w + (size_t)c * DMODEL;
            float p = 0.f;
#pragma unroll
            for (int j = 0; j < 32; ++j) p += xv[j] * wr[lane + 64 * j];
#pragma unroll
            for (int o = 32; o > 0; o >>= 1) p += __shfl_xor(p, o);
            if (lane == 0) s_coef[c] = p;
        }
    }
    __syncthreads();
    if (tid == 0) {
        float routing[NEXP], biased[NEXP];
        for (int e = 0; e < NEXP; ++e) {
            const float r = 1.f / (1.f + expf(-s_logits[e]));
            routing[e] = r;
            biased[e] = r + expert_bias[e];
        }
        int sel[4]; float sc[4]; float ssum = 0.f;
        for (int k = 0; k < 4; ++k) {
            int best = 0; float bv = -1e30f;
            for (int e = 0; e < NEXP; ++e)
                if (biased[e] > bv) { bv = biased[e]; best = e; }  // strict > = lax.top_k tie rule
            sel[k] = best; sc[k] = routing[best]; ssum += sc[k];
            biased[best] = -1e30f;
        }
        const float inv = 1.f / (ssum + 1e-20f);
        for (int k = 0; k < 4; ++k) {
            inds[t * 4 + k] = sel[k];
            scores[t * 4 + k] = sc[k] * inv;
        }
        const float l0 = s_coef[0] + coef_b[0];
        const float l1 = s_coef[1] + coef_b[1];
        const float m = fmaxf(l0, l1);
        const float e0 = expf(l0 - m), e1 = expf(l1 - m);
        coefo[t * 2 + 0] = e0 / (e0 + e1);
        coefo[t * 2 + 1] = e1 / (e0 + e1);
    }
}

// ---------------- x: f32 -> bf16 ----------------
__global__ __launch_bounds__(256)
void xcast_kernel(const float* __restrict__ x, unsigned short* __restrict__ xb)
{
    const int i = (blockIdx.x * 256 + threadIdx.x) * 4;
    const float4 v = *reinterpret_cast<const float4*>(x + i);
    ushort4 o;
    o.x = f2bf(v.x); o.y = f2bf(v.y); o.z = f2bf(v.z); o.w = f2bf(v.w);
    *reinterpret_cast<ushort4*>(xb + i) = o;
}

// ---------------- transpose-convert: f32 [K][N] -> bf16 [N][K] (per batch z) ------
__global__ __launch_bounds__(256)
void tconv_kernel(const float* __restrict__ src, unsigned short* __restrict__ dst,
                  const int K, const int N)
{
    __shared__ unsigned short T[64][80];   // [n][k], padded rows (160B)
    const size_t boff = (size_t)blockIdx.z * K * N;
    const float* s = src + boff;
    unsigned short* d = dst + boff;
    const int n0 = blockIdx.x * 64, k0 = blockIdx.y * 64;
    const int tid = threadIdx.x;

    const int n4 = (tid & 15) * 4;
    const int kr = tid >> 4;
#pragma unroll
    for (int i = 0; i < 4; ++i) {
        const int k = kr + i * 16;
        const float4 v = *reinterpret_cast<const float4*>(s + (size_t)(k0 + k) * N + n0 + n4);
        T[n4 + 0][k] = f2bf(v.x);
        T[n4 + 1][k] = f2bf(v.y);
        T[n4 + 2][k] = f2bf(v.z);
        T[n4 + 3][k] = f2bf(v.w);
    }
    __syncthreads();
    const int nw = tid >> 2;
    const int kc = (tid & 3) * 16;
    uint4* o = reinterpret_cast<uint4*>(d + (size_t)(n0 + nw) * K + k0 + kc);
    o[0] = *reinterpret_cast<const uint4*>(&T[nw][kc]);
    o[1] = *reinterpret_cast<const uint4*>(&T[nw][kc + 8]);
}

// ---------------- grouping: pair lists + BOTH tile tables + token->pos map ----
__global__ __launch_bounds__(1024)
void group_kernel(const int* __restrict__ inds, const float* __restrict__ scores,
                  int* __restrict__ meta, int* __restrict__ pair_token,
                  float* __restrict__ pair_score, int* __restrict__ tok_pos)
{
    __shared__ int cnt[NEXP];
    __shared__ int off_s[NEXP];
    __shared__ int cur[NEXP];
    const int tid = threadIdx.x;
    if (tid < NEXP) cnt[tid] = 0;
    __syncthreads();
    for (int i = tid; i < NPAIR; i += 1024) atomicAdd(&cnt[inds[i]], 1);
    __syncthreads();
    if (tid == 0) {
        int run = 0, nt1 = 0, nt2 = 0;
        for (int e = 0; e < NEXP; ++e) {
            off_s[e] = run;
            const int c = cnt[e];
            for (int m0 = 0; m0 < c; m0 += 128) {   // 128-row tiles (gateup_e)
                meta[M128_TE + nt1] = e;
                meta[M128_TP0 + nt1] = run + m0;
                meta[M128_TM + nt1] = (c - m0 < 128) ? (c - m0) : 128;
                ++nt1;
            }
            for (int m0 = 0; m0 < c; m0 += 64) {    // 64-row tiles (down_e)
                meta[M64_TE + nt2] = e;
                meta[M64_TP0 + nt2] = run + m0;
                meta[M64_TM + nt2] = (c - m0 < 64) ? (c - m0) : 64;
                ++nt2;
            }
            run += c;
        }
        meta[M128_NT] = nt1;
        meta[M64_NT] = nt2;
    }
    __syncthreads();
    if (tid < NEXP) cur[tid] = off_s[tid];
    __syncthreads();
    for (int i = tid; i < NPAIR; i += 1024) {
        const int e = inds[i];
        const int pos = atomicAdd(&cur[e], 1);
        pair_token[pos] = i >> 2;
        pair_score[pos] = scores[i];
        tok_pos[i] = pos;      // token t, slot k -> row in pair-major buffers
    }
}

// ---------------- expert gate+up GEMM (r7 config: BM=128, best measured) ----------
// BM=128, BK=32, dual-B (g,u) 64 cols each; 4 waves 2x2 (wave tile 64m x 32n/mat).
// global_load_lds staging, double-buffered LDS, one barrier per K-step.
__global__ __launch_bounds__(256, 4)
void gateup_e_kernel(const unsigned short* __restrict__ xb,
                     const unsigned short* __restrict__ Bg_all,
                     const unsigned short* __restrict__ Bu_all,
                     unsigned short* __restrict__ act,
                     const int* __restrict__ meta, const int* __restrict__ pair_token)
{
    constexpr int NT = DMODEL / 32;   // 64 K-steps
    constexpr int NB = HEXP;          // 512
    __shared__ unsigned short Al[2][128][32];
    __shared__ unsigned short Bgl[2][64][32];
    __shared__ unsigned short Bul[2][64][32];

    const int tid = threadIdx.x;
    const int lane = tid & 63;
    const int wave = tid >> 6;

    const int tt = blockIdx.y;
    if (tt >= meta[M128_NT]) return;
    const int e = meta[M128_TE + tt];
    const int p0 = meta[M128_TP0 + tt];
    const int mval = meta[M128_TM + tt];
    const size_t eoff = (size_t)e * NB * DMODEL;
    const unsigned short* Bg = Bg_all + eoff;
    const unsigned short* Bu = Bu_all + eoff;
    const int n0 = blockIdx.x * 64;

    const int sub  = lane >> 2;          // 0..15
    const int col8 = (lane & 3) * 8;     // k-offset in shorts
    const int arow0 = wave * 32 + sub;
    const int arow1 = arow0 + 16;
    int q0 = p0 + arow0; if (q0 > NPAIR - 1) q0 = NPAIR - 1;
    int q1 = p0 + arow1; if (q1 > NPAIR - 1) q1 = NPAIR - 1;
    const int tok0 = pair_token[q0];
    const int tok1 = pair_token[q1];
    const unsigned short* asrc0 = xb + (size_t)tok0 * DMODEL + col8;
    const unsigned short* asrc1 = xb + (size_t)tok1 * DMODEL + col8;
    const int brow = wave * 16 + sub;
    const unsigned short* gsrc = Bg + (size_t)(n0 + brow) * DMODEL + col8;
    const unsigned short* usrc = Bu + (size_t)(n0 + brow) * DMODEL + col8;

    auto stage = [&](int buf, int k0) {
        gload16(asrc0 + k0, &Al[buf][wave * 32][0]);
        gload16(asrc1 + k0, &Al[buf][wave * 32 + 16][0]);
        gload16(gsrc + k0, &Bgl[buf][wave * 16][0]);
        gload16(usrc + k0, &Bul[buf][wave * 16][0]);
    };

    const int wm = wave >> 1, wn = wave & 1;
    const int fr = lane & 15, fq = lane >> 4;

    const f32x4 zero4 = {0.f, 0.f, 0.f, 0.f};
    f32x4 hacc[4][2], uacc[4][2];
#pragma unroll
    for (int m = 0; m < 4; ++m)
#pragma unroll
        for (int n = 0; n < 2; ++n) { hacc[m][n] = zero4; uacc[m][n] = zero4; }

    auto compute = [&](int buf) {
        const int ko = fq * 8;
        s16x8 af[4], bg[2], bu[2];
#pragma unroll
        for (int m = 0; m < 4; ++m)
            af[m] = *reinterpret_cast<const s16x8*>(&Al[buf][wm * 64 + m * 16 + fr][ko]);
#pragma unroll
        for (int n = 0; n < 2; ++n) {
            bg[n] = *reinterpret_cast<const s16x8*>(&Bgl[buf][wn * 32 + n * 16 + fr][ko]);
            bu[n] = *reinterpret_cast<const s16x8*>(&Bul[buf][wn * 32 + n * 16 + fr][ko]);
        }
#pragma unroll
        for (int m = 0; m < 4; ++m)
#pragma unroll
            for (int n = 0; n < 2; ++n) {
                hacc[m][n] = mfma16x16x32(af[m], bg[n], hacc[m][n]);
                uacc[m][n] = mfma16x16x32(af[m], bu[n], uacc[m][n]);
            }
    };

    stage(0, 0);
    __syncthreads();
#pragma unroll 1
    for (int t = 0; t < NT; ++t) {
        const int cur = t & 1;
        if (t + 1 < NT) stage(cur ^ 1, (t + 1) * 32);
        compute(cur);
        __syncthreads();
    }

    // epilogue: act = silu(h)*u -> bf16. C/D frag: col=lane&15, row=fq*4+r
#pragma unroll
    for (int m = 0; m < 4; ++m)
#pragma unroll
        for (int n = 0; n < 2; ++n) {
            const int col = n0 + wn * 32 + n * 16 + fr;
#pragma unroll
            for (int r = 0; r < 4; ++r) {
                const int rt = wm * 64 + m * 16 + fq * 4 + r;
                if (rt < mval) {
                    const float hv = hacc[m][n][r];
                    const float a = hv / (1.f + __expf(-hv)) * uacc[m][n][r];
                    act[(size_t)(p0 + rt) * NB + col] = f2bf(a);
                }
            }
        }
}

// ---------------- shared gate+up GEMM (r10 config: BM=64) -------------------------
__global__ __launch_bounds__(256, 4)
void gateup_s_kernel(const unsigned short* __restrict__ xb,
                     const unsigned short* __restrict__ Bg,
                     const unsigned short* __restrict__ Bu,
                     unsigned short* __restrict__ act)
{
    constexpr int NT = DMODEL / 32;
    constexpr int NB = HSH;   // 1024
    __shared__ unsigned short Al[2][64][32];
    __shared__ unsigned short Bgl[2][64][32];
    __shared__ unsigned short Bul[2][64][32];

    const int tid = threadIdx.x;
    const int lane = tid & 63;
    const int wave = tid >> 6;
    const int p0 = blockIdx.y * 64;
    const int n0 = blockIdx.x * 64;

    const int sub  = lane >> 2;
    const int col8 = (lane & 3) * 8;
    const int arow = wave * 16 + sub;
    const unsigned short* asrc = xb + (size_t)(p0 + arow) * DMODEL + col8;
    const unsigned short* gsrc = Bg + (size_t)(n0 + arow) * DMODEL + col8;
    const unsigned short* usrc = Bu + (size_t)(n0 + arow) * DMODEL + col8;

    auto stage = [&](int buf, int k0) {
        gload16(asrc + k0, &Al[buf][wave * 16][0]);
        gload16(gsrc + k0, &Bgl[buf][wave * 16][0]);
        gload16(usrc + k0, &Bul[buf][wave * 16][0]);
    };

    const int wm = wave >> 1, wn = wave & 1;
    const int fr = lane & 15, fq = lane >> 4;

    const f32x4 zero4 = {0.f, 0.f, 0.f, 0.f};
    f32x4 hacc[2][2], uacc[2][2];
#pragma unroll
    for (int m = 0; m < 2; ++m)
#pragma unroll
        for (int n = 0; n < 2; ++n) { hacc[m][n] = zero4; uacc[m][n] = zero4; }

    auto compute = [&](int buf) {
        const int ko = fq * 8;
        s16x8 af[2], bg[2], bu[2];
#pragma unroll
        for (int m = 0; m < 2; ++m)
            af[m] = *reinterpret_cast<const s16x8*>(&Al[buf][wm * 32 + m * 16 + fr][ko]);
#pragma unroll
        for (int n = 0; n < 2; ++n) {
            bg[n] = *reinterpret_cast<const s16x8*>(&Bgl[buf][wn * 32 + n * 16 + fr][ko]);
            bu[n] = *reinterpret_cast<const s16x8*>(&Bul[buf][wn * 32 + n * 16 + fr][ko]);
        }
#pragma unroll
        for (int m = 0; m < 2; ++m)
#pragma unroll
            for (int n = 0; n < 2; ++n) {
                hacc[m][n] = mfma16x16x32(af[m], bg[n], hacc[m][n]);
                uacc[m][n] = mfma16x16x32(af[m], bu[n], uacc[m][n]);
            }
    };

    stage(0, 0);
    __syncthreads();
#pragma unroll 1
    for (int t = 0; t < NT; ++t) {
        const int cur = t & 1;
        if (t + 1 < NT) stage(cur ^ 1, (t + 1) * 32);
        compute(cur);
        __syncthreads();
    }

#pragma unroll
    for (int m = 0; m < 2; ++m)
#pragma unroll
        for (int n = 0; n < 2; ++n) {
            const int col = n0 + wn * 32 + n * 16 + fr;
#pragma unroll
            for (int r = 0; r < 4; ++r) {
                const int rt = wm * 32 + m * 16 + fq * 4 + r;
                const float hv = hacc[m][n][r];
                const float a = hv / (1.f + __expf(-hv)) * uacc[m][n][r];
                act[(size_t)(p0 + rt) * NB + col] = f2bf(a);
            }
        }
}

// ---------------- down GEMM (r10 config: BM=64, BN=64) ----------------------------
// EXPERT=true : A = act rows (pair-major, 64-row tile table); writes y_pair bf16.
// EXPERT=false: A = shared act; epilogue gathers token's 4 y_pair rows:
//               out = (sum y)*c0 + shared*c1  (no atomics anywhere).
template <bool EXPERT, int KA>
__global__ __launch_bounds__(256, 4)
void down_kernel(const unsigned short* __restrict__ act,
                 const unsigned short* __restrict__ Bd_all,
                 float* __restrict__ out, unsigned short* __restrict__ ypair,
                 const int* __restrict__ meta, const int* __restrict__ pair_token,
                 const float* __restrict__ pair_score, const float* __restrict__ coef,
                 const int* __restrict__ tok_pos)
{
    constexpr int NT = KA / 32;   // 16 or 32
    __shared__ unsigned short Al[2][64][32];
    __shared__ unsigned short Bl[2][64][32];

    const int tid = threadIdx.x;
    const int lane = tid & 63;
    const int wave = tid >> 6;

    int p0, mval;
    const unsigned short* Bd;
    if constexpr (EXPERT) {
        const int tt = blockIdx.y;
        if (tt >= meta[M64_NT]) return;
        const int e = meta[M64_TE + tt];
        p0 = meta[M64_TP0 + tt];
        mval = meta[M64_TM + tt];
        Bd = Bd_all + (size_t)e * DMODEL * KA;
    } else {
        p0 = blockIdx.y * 64;
        mval = 64;
        Bd = Bd_all;
    }
    const int n0 = blockIdx.x * 64;

    const int sub  = lane >> 2;
    const int col8 = (lane & 3) * 8;
    const int arow = wave * 16 + sub;
    int ar = p0 + arow;
    if constexpr (EXPERT) { if (ar > NPAIR - 1) ar = NPAIR - 1; }
    const unsigned short* asrc = act + (size_t)ar * KA + col8;
    const unsigned short* bsrc = Bd + (size_t)(n0 + arow) * KA + col8;

    auto stage = [&](int buf, int k0) {
        gload16(asrc + k0, &Al[buf][wave * 16][0]);
        gload16(bsrc + k0, &Bl[buf][wave * 16][0]);
    };

    const int wm = wave >> 1, wn = wave & 1;
    const int fr = lane & 15, fq = lane >> 4;

    const f32x4 zero4 = {0.f, 0.f, 0.f, 0.f};
    f32x4 acc[2][2];
#pragma unroll
    for (int m = 0; m < 2; ++m)
#pragma unroll
        for (int n = 0; n < 2; ++n) acc[m][n] = zero4;

    auto compute = [&](int buf) {
        const int ko = fq * 8;
        s16x8 af[2], bf[2];
#pragma unroll
        for (int m = 0; m < 2; ++m)
            af[m] = *reinterpret_cast<const s16x8*>(&Al[buf][wm * 32 + m * 16 + fr][ko]);
#pragma unroll
        for (int n = 0; n < 2; ++n)
            bf[n] = *reinterpret_cast<const s16x8*>(&Bl[buf][wn * 32 + n * 16 + fr][ko]);
#pragma unroll
        for (int m = 0; m < 2; ++m)
#pragma unroll
            for (int n = 0; n < 2; ++n)
                acc[m][n] = mfma16x16x32(af[m], bf[n], acc[m][n]);
    };

    stage(0, 0);
    __syncthreads();
#pragma unroll 1
    for (int t = 0; t < NT; ++t) {
        const int cur = t & 1;
        if (t + 1 < NT) stage(cur ^ 1, (t + 1) * 32);
        compute(cur);
        __syncthreads();
    }

#pragma unroll
    for (int m = 0; m < 2; ++m)
#pragma unroll
        for (int n = 0; n < 2; ++n) {
            const int col = n0 + wn * 32 + n * 16 + fr;
#pragma unroll
            for (int r = 0; r < 4; ++r) {
                const int rt = wm * 32 + m * 16 + fq * 4 + r;
                if (rt < mval) {
                    if constexpr (EXPERT) {
                        const int p = p0 + rt;
                        const float s = pair_score[p];
                        ypair[(size_t)p * DMODEL + col] = f2bf(acc[m][n][r] * s);
                    } else {
                        const int row = p0 + rt;     // token
                        float y4 = 0.f;
#pragma unroll
                        for (int k = 0; k < 4; ++k) {
                            const int pos = tok_pos[row * 4 + k];
                            y4 += bf2f(ypair[(size_t)pos * DMODEL + col]);
                        }
                        const float c0 = coef[row * 2 + 0];
                        const float c1 = coef[row * 2 + 1];
                        out[(size_t)row * DMODEL + col] = y4 * c0 + acc[m][n][r] * c1;
                    }
                }
            }
        }
}

// ---------------- launch ----------------
extern "C" void kernel_launch(void* const* d_in, const int* in_sizes, int n_in,
                              void* d_out, int out_size, void* d_ws, size_t ws_size,
                              hipStream_t stream)
{
    const float* x           = (const float*)d_in[0];
    const float* gate_w      = (const float*)d_in[1];
    const float* expert_bias = (const float*)d_in[2];
    const float* wg          = (const float*)d_in[3];
    const float* wu          = (const float*)d_in[4];
    const float* wd          = (const float*)d_in[5];
    const float* sg          = (const float*)d_in[6];
    const float* su          = (const float*)d_in[7];
    const float* sd          = (const float*)d_in[8];
    const float* coef_w      = (const float*)d_in[9];
    const float* coef_b      = (const float*)d_in[10];
    float* out = (float*)d_out;

    char* ws = (char*)d_ws;
    size_t off = 0;
    auto take = [&](size_t bytes) {
        char* p = ws + off;
        off = (off + bytes + 255) & ~(size_t)255;
        return p;
    };
    int*   inds     = (int*)  take((size_t)S_TOK * 4 * sizeof(int));
    float* scores   = (float*)take((size_t)S_TOK * 4 * sizeof(float));
    float* coefp    = (float*)take((size_t)S_TOK * 2 * sizeof(float));
    int*   meta     = (int*)  take((size_t)META_SIZE * sizeof(int));
    int*   pair_tok = (int*)  take((size_t)NPAIR * sizeof(int));
    float* pair_sc  = (float*)take((size_t)NPAIR * sizeof(float));
    int*   tok_pos  = (int*)  take((size_t)NPAIR * sizeof(int));
    unsigned short* xb    = (unsigned short*)take((size_t)S_TOK * DMODEL * 2);
    unsigned short* act   = (unsigned short*)take((size_t)NPAIR * HEXP * 2);
    unsigned short* shact = (unsigned short*)take((size_t)S_TOK * HSH * 2);
    unsigned short* ypair = (unsigned short*)take((size_t)NPAIR * DMODEL * 2);  // 33.5MB
    unsigned short* sgb   = (unsigned short*)take((size_t)HSH * DMODEL * 2);    // [HS][D]
    unsigned short* sub_  = (unsigned short*)take((size_t)HSH * DMODEL * 2);    // [HS][D]
    unsigned short* sdb   = (unsigned short*)take((size_t)DMODEL * HSH * 2);    // [D][HS]
    unsigned short* W1    = (unsigned short*)take((size_t)NEXP * DMODEL * HEXP * 2); // 64MB
    unsigned short* W2    = (unsigned short*)take((size_t)NEXP * DMODEL * HEXP * 2); // 64MB
    (void)ws_size; (void)in_sizes; (void)n_in; (void)out_size;

    router_kernel<<<S_TOK, 256, 0, stream>>>(x, gate_w, expert_bias, coef_w, coef_b,
                                             inds, scores, coefp);
    xcast_kernel<<<(S_TOK * DMODEL / 4) / 256, 256, 0, stream>>>(x, xb);
    group_kernel<<<1, 1024, 0, stream>>>(inds, scores, meta, pair_tok, pair_sc, tok_pos);

    // transpose-convert weights: f32 [K][N] -> bf16 [N][K]
    tconv_kernel<<<dim3(HSH / 64, DMODEL / 64, 1), 256, 0, stream>>>(sg, sgb, DMODEL, HSH);
    tconv_kernel<<<dim3(HSH / 64, DMODEL / 64, 1), 256, 0, stream>>>(su, sub_, DMODEL, HSH);
    tconv_kernel<<<dim3(DMODEL / 64, HSH / 64, 1), 256, 0, stream>>>(sd, sdb, HSH, DMODEL);
    tconv_kernel<<<dim3(HEXP / 64, DMODEL / 64, NEXP), 256, 0, stream>>>(wg, W1, DMODEL, HEXP);
    tconv_kernel<<<dim3(HEXP / 64, DMODEL / 64, NEXP), 256, 0, stream>>>(wu, W2, DMODEL, HEXP);

    // expert gate+up (+SwiGLU): BM=128 (best measured config for this GEMM)
    gateup_e_kernel<<<dim3(HEXP / 64, NT128), 256, 0, stream>>>(
        xb, W1, W2, act, meta, pair_tok);
    // shared gate+up: BM=64
    gateup_s_kernel<<<dim3(HSH / 64, S_TOK / 64), 256, 0, stream>>>(
        xb, sgb, sub_, shact);

    // wd -> bf16 [E][D][H] into W1 (wgb dead after expert gateup)
    tconv_kernel<<<dim3(DMODEL / 64, HEXP / 64, NEXP), 256, 0, stream>>>(wd, W1, HEXP, DMODEL);

    // expert down: y_pair[p][D] = (act_p . wd_e) * score_p   (plain bf16 stores)
    down_kernel<true, HEXP><<<dim3(DMODEL / 64, NT64), 256, 0, stream>>>(
        act, W1, out, ypair, meta, pair_tok, pair_sc, nullptr, tok_pos);
    // shared down + gather 4 y_pair rows + coef mix -> out (each element written once)
    down_kernel<false, HSH><<<dim3(DMODEL / 64, S_TOK / 64), 256, 0, stream>>>(
        shact, sdb, out, ypair, nullptr, nullptr, nullptr, coefp, tok_pos);
}

// Round 12
// 362.116 us; speedup vs baseline: 1.7787x; 1.0825x over previous
//
#include <hip/hip_runtime.h>
#include <hip/hip_bf16.h>
#include <stdint.h>

// ---------------- problem dims (fixed by setup_inputs) ----------------
#define S_TOK   2048   // tokens (B*S)
#define DMODEL  2048   // D
#define HEXP    512    // H per expert
#define NEXP    32     // E
#define HSH     1024   // shared hidden
#define NPAIR   (S_TOK * 4)   // 8192 (token,expert) pairs, top_k=4
#define NT128   96            // sum ceil(cnt_e/128) <= 8192/128 + 32
#define NT64    160           // sum ceil(cnt_e/64)  <= 8192/64  + 32

// meta layout (ints): two tile tables (128-row for gateup_e, 64-row for down_e)
#define M128_NT  0
#define M128_TE  1
#define M128_TP0 (1 + NT128)
#define M128_TM  (1 + 2 * NT128)
#define M64_NT   (1 + 3 * NT128)
#define M64_TE   (M64_NT + 1)
#define M64_TP0  (M64_NT + 1 + NT64)
#define M64_TM   (M64_NT + 1 + 2 * NT64)
#define META_SIZE (M64_NT + 1 + 3 * NT64)

typedef short  s16x8 __attribute__((ext_vector_type(8)));
typedef __bf16 b16x8 __attribute__((ext_vector_type(8)));
typedef float  f32x4 __attribute__((ext_vector_type(4)));

__device__ __forceinline__ f32x4 mfma16x16x32(s16x8 a, s16x8 b, f32x4 c) {
    return __builtin_amdgcn_mfma_f32_16x16x32_bf16(
        __builtin_bit_cast(b16x8, a), __builtin_bit_cast(b16x8, b), c, 0, 0, 0);
}

__device__ __forceinline__ unsigned short f2bf(float f) {
    union { float f; unsigned int u; } v; v.f = f;
    unsigned int u = v.u;
    return (unsigned short)((u + 0x7FFFu + ((u >> 16) & 1u)) >> 16);  // RNE
}

__device__ __forceinline__ float bf2f(unsigned short b) {
    union { unsigned int u; float f; } v; v.u = ((unsigned int)b) << 16;
    return v.f;
}

// async global->LDS, 16B per lane. LDS dest is wave-uniform base + lane*16.
__device__ __forceinline__ void gload16(const unsigned short* g, unsigned short* l) {
    __builtin_amdgcn_global_load_lds(
        (const __attribute__((address_space(1))) void*)(uintptr_t)g,
        (__attribute__((address_space(3))) void*)(uintptr_t)l, 16, 0, 0);
}

// ---- LDS bank swizzle for [row][32-short] tiles (64B rows) ----
// Without swizzle a b128 fragment read (lanes fr=0..15, granule fq) hits banks
// 16*(fr&1)+4*fq -> 2 banks / 8-way. Swizzle granule by key(row)=((row&15)>>1)&3:
// write side uses pre-swizzled GLOBAL source granule (gload_lds writes linearly),
// read side XORs fq by the same key -> 2-way (free). [rule #21: both sides or neither]
__device__ __forceinline__ int src_col8(int lane) {          // staging source offset (shorts)
    return 8 * ((lane & 3) ^ ((lane >> 3) & 3));             // (lane>>3)&3 == ((sub)>>1)&3, sub=lane>>2
}
__device__ __forceinline__ int frag_ko(int fr, int fq) {     // fragment read offset (shorts)
    return 8 * (fq ^ ((fr >> 1) & 3));
}

// ---------------- transpose-convert tile: f32 [K][N] -> bf16 [N][K] ----------------
__device__ __forceinline__ void tconv_tile(const float* __restrict__ s,
                                           unsigned short* __restrict__ d,
                                           const int K, const int N,
                                           const int k0, const int n0,
                                           unsigned short* pool)   // >= 5120 shorts
{
    auto T = (unsigned short (*)[80])pool;   // [64][80], padded rows
    const int tid = threadIdx.x;
    const int n4 = (tid & 15) * 4;
    const int kr = tid >> 4;
#pragma unroll
    for (int i = 0; i < 4; ++i) {
        const int k = kr + i * 16;
        const float4 v = *reinterpret_cast<const float4*>(s + (size_t)(k0 + k) * N + n0 + n4);
        T[n4 + 0][k] = f2bf(v.x);
        T[n4 + 1][k] = f2bf(v.y);
        T[n4 + 2][k] = f2bf(v.z);
        T[n4 + 3][k] = f2bf(v.w);
    }
    __syncthreads();
    const int nw = tid >> 2;
    const int kc = (tid & 3) * 16;
    uint4* o = reinterpret_cast<uint4*>(d + (size_t)(n0 + nw) * K + k0 + kc);
    o[0] = *reinterpret_cast<const uint4*>(&T[nw][kc]);
    o[1] = *reinterpret_cast<const uint4*>(&T[nw][kc + 8]);
}

// ---------------- router: logits, sigmoid, biased top-4, coef softmax ----------------
__global__ __launch_bounds__(256)
void router_kernel(const float* __restrict__ x, const float* __restrict__ gate_w,
                   const float* __restrict__ expert_bias,
                   const float* __restrict__ coef_w, const float* __restrict__ coef_b,
                   int* __restrict__ inds, float* __restrict__ scores,
                   float* __restrict__ coefo)
{
    const int t = blockIdx.x;
    const int tid = threadIdx.x;
    const int lane = tid & 63;
    const int wave = tid >> 6;
    const float* xr = x + (size_t)t * DMODEL;

    float xv[32];
#pragma unroll
    for (int j = 0; j < 32; ++j) xv[j] = xr[lane + 64 * j];

    __shared__ float s_logits[NEXP];
    __shared__ float s_coef[2];

    for (int i = 0; i < 8; ++i) {
        const int e = wave * 8 + i;
        const float* wr = gate_w + (size_t)e * DMODEL;
        float p = 0.f;
#pragma unroll
        for (int j = 0; j < 32; ++j) p += xv[j] * wr[lane + 64 * j];
#pragma unroll
        for (int o = 32; o > 0; o >>= 1) p += __shfl_xor(p, o);
        if (lane == 0) s_logits[e] = p;
    }
    if (wave == 0) {
        for (int c = 0; c < 2; ++c) {
            const float* wr = coef_w + (size_t)c * DMODEL;
            float p = 0.f;
#pragma unroll
            for (int j = 0; j < 32; ++j) p += xv[j] * wr[lane + 64 * j];
#pragma unroll
            for (int o = 32; o > 0; o >>= 1) p += __shfl_xor(p, o);
            if (lane == 0) s_coef[c] = p;
        }
    }
    __syncthreads();
    if (tid == 0) {
        float routing[NEXP], biased[NEXP];
        for (int e = 0; e < NEXP; ++e) {
            const float r = 1.f / (1.f + expf(-s_logits[e]));
            routing[e] = r;
            biased[e] = r + expert_bias[e];
        }
        int sel[4]; float sc[4]; float ssum = 0.f;
        for (int k = 0; k < 4; ++k) {
            int best = 0; float bv = -1e30f;
            for (int e = 0; e < NEXP; ++e)
                if (biased[e] > bv) { bv = biased[e]; best = e; }  // strict > = lax.top_k tie rule
            sel[k] = best; sc[k] = routing[best]; ssum += sc[k];
            biased[best] = -1e30f;
        }
        const float inv = 1.f / (ssum + 1e-20f);
        for (int k = 0; k < 4; ++k) {
            inds[t * 4 + k] = sel[k];
            scores[t * 4 + k] = sc[k] * inv;
        }
        const float l0 = s_coef[0] + coef_b[0];
        const float l1 = s_coef[1] + coef_b[1];
        const float m = fmaxf(l0, l1);
        const float e0 = expf(l0 - m), e1 = expf(l1 - m);
        coefo[t * 2 + 0] = e0 / (e0 + e1);
        coefo[t * 2 + 1] = e1 / (e0 + e1);
    }
}

// ---------------- x: f32 -> bf16 ----------------
__global__ __launch_bounds__(256)
void xcast_kernel(const float* __restrict__ x, unsigned short* __restrict__ xb)
{
    const int i = (blockIdx.x * 256 + threadIdx.x) * 4;
    const float4 v = *reinterpret_cast<const float4*>(x + i);
    ushort4 o;
    o.x = f2bf(v.x); o.y = f2bf(v.y); o.z = f2bf(v.z); o.w = f2bf(v.w);
    *reinterpret_cast<ushort4*>(xb + i) = o;
}

// ---------------- standalone tconv (wg, wu) ----------------
__global__ __launch_bounds__(256)
void tconv_kernel(const float* __restrict__ src, unsigned short* __restrict__ dst,
                  const int K, const int N)
{
    __shared__ unsigned short pool[64 * 80];
    const size_t boff = (size_t)blockIdx.z * K * N;
    tconv_tile(src + boff, dst + boff, K, N, blockIdx.y * 64, blockIdx.x * 64, pool);
}

// ---------------- grouping: pair lists + BOTH tile tables + token->pos map ----
__global__ __launch_bounds__(1024)
void group_kernel(const int* __restrict__ inds, const float* __restrict__ scores,
                  int* __restrict__ meta, int* __restrict__ pair_token,
                  float* __restrict__ pair_score, int* __restrict__ tok_pos)
{
    __shared__ int cnt[NEXP];
    __shared__ int off_s[NEXP];
    __shared__ int cur[NEXP];
    const int tid = threadIdx.x;
    if (tid < NEXP) cnt[tid] = 0;
    __syncthreads();
    for (int i = tid; i < NPAIR; i += 1024) atomicAdd(&cnt[inds[i]], 1);
    __syncthreads();
    if (tid == 0) {
        int run = 0, nt1 = 0, nt2 = 0;
        for (int e = 0; e < NEXP; ++e) {
            off_s[e] = run;
            const int c = cnt[e];
            for (int m0 = 0; m0 < c; m0 += 128) {   // 128-row tiles (gateup_e)
                meta[M128_TE + nt1] = e;
                meta[M128_TP0 + nt1] = run + m0;
                meta[M128_TM + nt1] = (c - m0 < 128) ? (c - m0) : 128;
                ++nt1;
            }
            for (int m0 = 0; m0 < c; m0 += 64) {    // 64-row tiles (down_e)
                meta[M64_TE + nt2] = e;
                meta[M64_TP0 + nt2] = run + m0;
                meta[M64_TM + nt2] = (c - m0 < 64) ? (c - m0) : 64;
                ++nt2;
            }
            run += c;
        }
        meta[M128_NT] = nt1;
        meta[M64_NT] = nt2;
    }
    __syncthreads();
    if (tid < NEXP) cur[tid] = off_s[tid];
    __syncthreads();
    for (int i = tid; i < NPAIR; i += 1024) {
        const int e = inds[i];
        const int pos = atomicAdd(&cur[e], 1);
        pair_token[pos] = i >> 2;
        pair_score[pos] = scores[i];
        tok_pos[i] = pos;      // token t, slot k -> row in pair-major buffers
    }
}

// ---------------- expert gate+up GEMM (BM=128) + passenger tconv(sg,su,sd) --------
// GEMM role (blockIdx.y < NT128): BM=128, BK=32, dual-B; 4 waves 2x2; swizzled LDS.
// tconv role (blockIdx.y >= NT128): converts shared-expert weights concurrently.
__global__ __launch_bounds__(256, 4)
void gateup_e_kernel(const unsigned short* __restrict__ xb,
                     const unsigned short* __restrict__ Bg_all,
                     const unsigned short* __restrict__ Bu_all,
                     unsigned short* __restrict__ act,
                     const int* __restrict__ meta, const int* __restrict__ pair_token,
                     const float* __restrict__ sg, const float* __restrict__ su,
                     const float* __restrict__ sd,
                     unsigned short* __restrict__ sgb, unsigned short* __restrict__ sub_,
                     unsigned short* __restrict__ sdb)
{
    constexpr int NT = DMODEL / 32;   // 64 K-steps
    constexpr int NB = HEXP;          // 512
    __shared__ unsigned short pool[16384];   // 32 KB
    auto Al  = (unsigned short (*)[128][32])(pool);
    auto Bgl = (unsigned short (*)[64][32])(pool + 8192);
    auto Bul = (unsigned short (*)[64][32])(pool + 12288);

    const int tid = threadIdx.x;
    const int lane = tid & 63;
    const int wave = tid >> 6;

    if (blockIdx.y >= NT128) {      // ---- passenger tconv role ----
        const int tile = (blockIdx.y - NT128) * 8 + blockIdx.x;  // 0..1535
        const int which = tile / 512;
        const int t = tile % 512;
        if (which == 0)      tconv_tile(sg, sgb, DMODEL, HSH, (t >> 4) * 64, (t & 15) * 64, pool);
        else if (which == 1) tconv_tile(su, sub_, DMODEL, HSH, (t >> 4) * 64, (t & 15) * 64, pool);
        else                 tconv_tile(sd, sdb, HSH, DMODEL, (t >> 5) * 64, (t & 31) * 64, pool);
        return;
    }

    const int tt = blockIdx.y;
    if (tt >= meta[M128_NT]) return;
    const int e = meta[M128_TE + tt];
    const int p0 = meta[M128_TP0 + tt];
    const int mval = meta[M128_TM + tt];
    const size_t eoff = (size_t)e * NB * DMODEL;
    const unsigned short* Bg = Bg_all + eoff;
    const unsigned short* Bu = Bu_all + eoff;
    const int n0 = blockIdx.x * 64;

    const int sub  = lane >> 2;            // 0..15 (row within 16-row chunk)
    const int col8 = src_col8(lane);       // pre-swizzled source granule
    const int arow0 = wave * 32 + sub;
    const int arow1 = arow0 + 16;
    int q0 = p0 + arow0; if (q0 > NPAIR - 1) q0 = NPAIR - 1;
    int q1 = p0 + arow1; if (q1 > NPAIR - 1) q1 = NPAIR - 1;
    const int tok0 = pair_token[q0];
    const int tok1 = pair_token[q1];
    const unsigned short* asrc0 = xb + (size_t)tok0 * DMODEL + col8;
    const unsigned short* asrc1 = xb + (size_t)tok1 * DMODEL + col8;
    const int brow = wave * 16 + sub;
    const unsigned short* gsrc = Bg + (size_t)(n0 + brow) * DMODEL + col8;
    const unsigned short* usrc = Bu + (size_t)(n0 + brow) * DMODEL + col8;

    auto stage = [&](int buf, int k0) {
        gload16(asrc0 + k0, &Al[buf][wave * 32][0]);
        gload16(asrc1 + k0, &Al[buf][wave * 32 + 16][0]);
        gload16(gsrc + k0, &Bgl[buf][wave * 16][0]);
        gload16(usrc + k0, &Bul[buf][wave * 16][0]);
    };

    const int wm = wave >> 1, wn = wave & 1;
    const int fr = lane & 15, fq = lane >> 4;
    const int ko = frag_ko(fr, fq);        // swizzled fragment read offset

    const f32x4 zero4 = {0.f, 0.f, 0.f, 0.f};
    f32x4 hacc[4][2], uacc[4][2];
#pragma unroll
    for (int m = 0; m < 4; ++m)
#pragma unroll
        for (int n = 0; n < 2; ++n) { hacc[m][n] = zero4; uacc[m][n] = zero4; }

    auto compute = [&](int buf) {
        s16x8 af[4], bg[2], bu[2];
#pragma unroll
        for (int m = 0; m < 4; ++m)
            af[m] = *reinterpret_cast<const s16x8*>(&Al[buf][wm * 64 + m * 16 + fr][ko]);
#pragma unroll
        for (int n = 0; n < 2; ++n) {
            bg[n] = *reinterpret_cast<const s16x8*>(&Bgl[buf][wn * 32 + n * 16 + fr][ko]);
            bu[n] = *reinterpret_cast<const s16x8*>(&Bul[buf][wn * 32 + n * 16 + fr][ko]);
        }
#pragma unroll
        for (int m = 0; m < 4; ++m)
#pragma unroll
            for (int n = 0; n < 2; ++n) {
                hacc[m][n] = mfma16x16x32(af[m], bg[n], hacc[m][n]);
                uacc[m][n] = mfma16x16x32(af[m], bu[n], uacc[m][n]);
            }
    };

    stage(0, 0);
    __syncthreads();
#pragma unroll 1
    for (int t = 0; t < NT; ++t) {
        const int cur = t & 1;
        if (t + 1 < NT) stage(cur ^ 1, (t + 1) * 32);
        compute(cur);
        __syncthreads();
    }

    // epilogue: act = silu(h)*u -> bf16. C/D frag: col=lane&15, row=fq*4+r
#pragma unroll
    for (int m = 0; m < 4; ++m)
#pragma unroll
        for (int n = 0; n < 2; ++n) {
            const int col = n0 + wn * 32 + n * 16 + fr;
#pragma unroll
            for (int r = 0; r < 4; ++r) {
                const int rt = wm * 64 + m * 16 + fq * 4 + r;
                if (rt < mval) {
                    const float hv = hacc[m][n][r];
                    const float a = hv / (1.f + __expf(-hv)) * uacc[m][n][r];
                    act[(size_t)(p0 + rt) * NB + col] = f2bf(a);
                }
            }
        }
}

// ---------------- shared gate+up GEMM (BM=64) + passenger tconv(wd) ---------------
__global__ __launch_bounds__(256, 4)
void gateup_s_kernel(const unsigned short* __restrict__ xb,
                     const unsigned short* __restrict__ Bg,
                     const unsigned short* __restrict__ Bu,
                     unsigned short* __restrict__ act,
                     const float* __restrict__ wd, unsigned short* __restrict__ wdb)
{
    constexpr int NT = DMODEL / 32;
    constexpr int NB = HSH;   // 1024
    __shared__ unsigned short pool[12288];   // 24 KB
    auto Al  = (unsigned short (*)[64][32])(pool);
    auto Bgl = (unsigned short (*)[64][32])(pool + 4096);
    auto Bul = (unsigned short (*)[64][32])(pool + 8192);

    const int tid = threadIdx.x;
    const int lane = tid & 63;
    const int wave = tid >> 6;

    if (blockIdx.y >= S_TOK / 64) {   // ---- passenger tconv(wd) role ----
        const int tile = (blockIdx.y - S_TOK / 64) * 16 + blockIdx.x;  // 0..8191
        const int e = tile >> 8;
        const int t = tile & 255;
        tconv_tile(wd + (size_t)e * HEXP * DMODEL, wdb + (size_t)e * DMODEL * HEXP,
                   HEXP, DMODEL, (t >> 5) * 64, (t & 31) * 64, pool);
        return;
    }

    const int p0 = blockIdx.y * 64;
    const int n0 = blockIdx.x * 64;

    const int sub  = lane >> 2;
    const int col8 = src_col8(lane);
    const int arow = wave * 16 + sub;
    const unsigned short* asrc = xb + (size_t)(p0 + arow) * DMODEL + col8;
    const unsigned short* gsrc = Bg + (size_t)(n0 + arow) * DMODEL + col8;
    const unsigned short* usrc = Bu + (size_t)(n0 + arow) * DMODEL + col8;

    auto stage = [&](int buf, int k0) {
        gload16(asrc + k0, &Al[buf][wave * 16][0]);
        gload16(gsrc + k0, &Bgl[buf][wave * 16][0]);
        gload16(usrc + k0, &Bul[buf][wave * 16][0]);
    };

    const int wm = wave >> 1, wn = wave & 1;
    const int fr = lane & 15, fq = lane >> 4;
    const int ko = frag_ko(fr, fq);

    const f32x4 zero4 = {0.f, 0.f, 0.f, 0.f};
    f32x4 hacc[2][2], uacc[2][2];
#pragma unroll
    for (int m = 0; m < 2; ++m)
#pragma unroll
        for (int n = 0; n < 2; ++n) { hacc[m][n] = zero4; uacc[m][n] = zero4; }

    auto compute = [&](int buf) {
        s16x8 af[2], bg[2], bu[2];
#pragma unroll
        for (int m = 0; m < 2; ++m)
            af[m] = *reinterpret_cast<const s16x8*>(&Al[buf][wm * 32 + m * 16 + fr][ko]);
#pragma unroll
        for (int n = 0; n < 2; ++n) {
            bg[n] = *reinterpret_cast<const s16x8*>(&Bgl[buf][wn * 32 + n * 16 + fr][ko]);
            bu[n] = *reinterpret_cast<const s16x8*>(&Bul[buf][wn * 32 + n * 16 + fr][ko]);
        }
#pragma unroll
        for (int m = 0; m < 2; ++m)
#pragma unroll
            for (int n = 0; n < 2; ++n) {
                hacc[m][n] = mfma16x16x32(af[m], bg[n], hacc[m][n]);
                uacc[m][n] = mfma16x16x32(af[m], bu[n], uacc[m][n]);
            }
    };

    stage(0, 0);
    __syncthreads();
#pragma unroll 1
    for (int t = 0; t < NT; ++t) {
        const int cur = t & 1;
        if (t + 1 < NT) stage(cur ^ 1, (t + 1) * 32);
        compute(cur);
        __syncthreads();
    }

#pragma unroll
    for (int m = 0; m < 2; ++m)
#pragma unroll
        for (int n = 0; n < 2; ++n) {
            const int col = n0 + wn * 32 + n * 16 + fr;
#pragma unroll
            for (int r = 0; r < 4; ++r) {
                const int rt = wm * 32 + m * 16 + fq * 4 + r;
                const float hv = hacc[m][n][r];
                const float a = hv / (1.f + __expf(-hv)) * uacc[m][n][r];
                act[(size_t)(p0 + rt) * NB + col] = f2bf(a);
            }
        }
}

// ---------------- down GEMM (BM=64, BN=64), swizzled LDS --------------------------
// EXPERT=true : A = act rows (pair-major, 64-row tile table); writes y_pair bf16.
// EXPERT=false: A = shared act; epilogue gathers token's 4 y_pair rows:
//               out = (sum y)*c0 + shared*c1  (no atomics anywhere).
template <bool EXPERT, int KA>
__global__ __launch_bounds__(256, 4)
void down_kernel(const unsigned short* __restrict__ act,
                 const unsigned short* __restrict__ Bd_all,
                 float* __restrict__ out, unsigned short* __restrict__ ypair,
                 const int* __restrict__ meta, const int* __restrict__ pair_token,
                 const float* __restrict__ pair_score, const float* __restrict__ coef,
                 const int* __restrict__ tok_pos)
{
    constexpr int NT = KA / 32;   // 16 or 32
    __shared__ unsigned short Al[2][64][32];
    __shared__ unsigned short Bl[2][64][32];

    const int tid = threadIdx.x;
    const int lane = tid & 63;
    const int wave = tid >> 6;

    int p0, mval;
    const unsigned short* Bd;
    if constexpr (EXPERT) {
        const int tt = blockIdx.y;
        if (tt >= meta[M64_NT]) return;
        const int e = meta[M64_TE + tt];
        p0 = meta[M64_TP0 + tt];
        mval = meta[M64_TM + tt];
        Bd = Bd_all + (size_t)e * DMODEL * KA;
    } else {
        p0 = blockIdx.y * 64;
        mval = 64;
        Bd = Bd_all;
    }
    const int n0 = blockIdx.x * 64;

    const int sub  = lane >> 2;
    const int col8 = src_col8(lane);
    const int arow = wave * 16 + sub;
    int ar = p0 + arow;
    if constexpr (EXPERT) { if (ar > NPAIR - 1) ar = NPAIR - 1; }
    const unsigned short* asrc = act + (size_t)ar * KA + col8;
    const unsigned short* bsrc = Bd + (size_t)(n0 + arow) * KA + col8;

    auto stage = [&](int buf, int k0) {
        gload16(asrc + k0, &Al[buf][wave * 16][0]);
        gload16(bsrc + k0, &Bl[buf][wave * 16][0]);
    };

    const int wm = wave >> 1, wn = wave & 1;
    const int fr = lane & 15, fq = lane >> 4;
    const int ko = frag_ko(fr, fq);

    const f32x4 zero4 = {0.f, 0.f, 0.f, 0.f};
    f32x4 acc[2][2];
#pragma unroll
    for (int m = 0; m < 2; ++m)
#pragma unroll
        for (int n = 0; n < 2; ++n) acc[m][n] = zero4;

    auto compute = [&](int buf) {
        s16x8 af[2], bf[2];
#pragma unroll
        for (int m = 0; m < 2; ++m)
            af[m] = *reinterpret_cast<const s16x8*>(&Al[buf][wm * 32 + m * 16 + fr][ko]);
#pragma unroll
        for (int n = 0; n < 2; ++n)
            bf[n] = *reinterpret_cast<const s16x8*>(&Bl[buf][wn * 32 + n * 16 + fr][ko]);
#pragma unroll
        for (int m = 0; m < 2; ++m)
#pragma unroll
            for (int n = 0; n < 2; ++n)
                acc[m][n] = mfma16x16x32(af[m], bf[n], acc[m][n]);
    };

    stage(0, 0);
    __syncthreads();
#pragma unroll 1
    for (int t = 0; t < NT; ++t) {
        const int cur = t & 1;
        if (t + 1 < NT) stage(cur ^ 1, (t + 1) * 32);
        compute(cur);
        __syncthreads();
    }

#pragma unroll
    for (int m = 0; m < 2; ++m)
#pragma unroll
        for (int n = 0; n < 2; ++n) {
            const int col = n0 + wn * 32 + n * 16 + fr;
#pragma unroll
            for (int r = 0; r < 4; ++r) {
                const int rt = wm * 32 + m * 16 + fq * 4 + r;
                if (rt < mval) {
                    if constexpr (EXPERT) {
                        const int p = p0 + rt;
                        const float s = pair_score[p];
                        ypair[(size_t)p * DMODEL + col] = f2bf(acc[m][n][r] * s);
                    } else {
                        const int row = p0 + rt;     // token
                        float y4 = 0.f;
#pragma unroll
                        for (int k = 0; k < 4; ++k) {
                            const int pos = tok_pos[row * 4 + k];
                            y4 += bf2f(ypair[(size_t)pos * DMODEL + col]);
                        }
                        const float c0 = coef[row * 2 + 0];
                        const float c1 = coef[row * 2 + 1];
                        out[(size_t)row * DMODEL + col] = y4 * c0 + acc[m][n][r] * c1;
                    }
                }
            }
        }
}

// ---------------- launch ----------------
extern "C" void kernel_launch(void* const* d_in, const int* in_sizes, int n_in,
                              void* d_out, int out_size, void* d_ws, size_t ws_size,
                              hipStream_t stream)
{
    const float* x           = (const float*)d_in[0];
    const float* gate_w      = (const float*)d_in[1];
    const float* expert_bias = (const float*)d_in[2];
    const float* wg          = (const float*)d_in[3];
    const float* wu          = (const float*)d_in[4];
    const float* wd          = (const float*)d_in[5];
    const float* sg          = (const float*)d_in[6];
    const float* su          = (const float*)d_in[7];
    const float* sd          = (const float*)d_in[8];
    const float* coef_w      = (const float*)d_in[9];
    const float* coef_b      = (const float*)d_in[10];
    float* out = (float*)d_out;

    char* ws = (char*)d_ws;
    size_t off = 0;
    auto take = [&](size_t bytes) {
        char* p = ws + off;
        off = (off + bytes + 255) & ~(size_t)255;
        return p;
    };
    int*   inds     = (int*)  take((size_t)S_TOK * 4 * sizeof(int));
    float* scores   = (float*)take((size_t)S_TOK * 4 * sizeof(float));
    float* coefp    = (float*)take((size_t)S_TOK * 2 * sizeof(float));
    int*   meta     = (int*)  take((size_t)META_SIZE * sizeof(int));
    int*   pair_tok = (int*)  take((size_t)NPAIR * sizeof(int));
    float* pair_sc  = (float*)take((size_t)NPAIR * sizeof(float));
    int*   tok_pos  = (int*)  take((size_t)NPAIR * sizeof(int));
    unsigned short* xb    = (unsigned short*)take((size_t)S_TOK * DMODEL * 2);
    unsigned short* act   = (unsigned short*)take((size_t)NPAIR * HEXP * 2);
    unsigned short* shact = (unsigned short*)take((size_t)S_TOK * HSH * 2);
    unsigned short* ypair = (unsigned short*)take((size_t)NPAIR * DMODEL * 2);  // 33.5MB
    unsigned short* sgb   = (unsigned short*)take((size_t)HSH * DMODEL * 2);    // [HS][D]
    unsigned short* sub_  = (unsigned short*)take((size_t)HSH * DMODEL * 2);    // [HS][D]
    unsigned short* sdb   = (unsigned short*)take((size_t)DMODEL * HSH * 2);    // [D][HS]
    unsigned short* W1    = (unsigned short*)take((size_t)NEXP * DMODEL * HEXP * 2); // 64MB
    unsigned short* W2    = (unsigned short*)take((size_t)NEXP * DMODEL * HEXP * 2); // 64MB
    (void)ws_size; (void)in_sizes; (void)n_in; (void)out_size;

    router_kernel<<<S_TOK, 256, 0, stream>>>(x, gate_w, expert_bias, coef_w, coef_b,
                                             inds, scores, coefp);
    xcast_kernel<<<(S_TOK * DMODEL / 4) / 256, 256, 0, stream>>>(x, xb);
    group_kernel<<<1, 1024, 0, stream>>>(inds, scores, meta, pair_tok, pair_sc, tok_pos);

    // transpose-convert expert gate/up weights: f32 [K][N] -> bf16 [N][K]
    tconv_kernel<<<dim3(HEXP / 64, DMODEL / 64, NEXP), 256, 0, stream>>>(wg, W1, DMODEL, HEXP);
    tconv_kernel<<<dim3(HEXP / 64, DMODEL / 64, NEXP), 256, 0, stream>>>(wu, W2, DMODEL, HEXP);

    // expert gate+up (+SwiGLU), with passenger tconv of sg/su/sd (1536 tiles -> +192 y)
    gateup_e_kernel<<<dim3(HEXP / 64, NT128 + 192), 256, 0, stream>>>(
        xb, W1, W2, act, meta, pair_tok, sg, su, sd, sgb, sub_, sdb);
    // shared gate+up (BM=64), with passenger tconv of wd into W1 (free after gateup_e)
    gateup_s_kernel<<<dim3(HSH / 64, S_TOK / 64 + 512), 256, 0, stream>>>(
        xb, sgb, sub_, shact, wd, W1);

    // expert down: y_pair[p][D] = (act_p . wd_e) * score_p   (plain bf16 stores)
    down_kernel<true, HEXP><<<dim3(DMODEL / 64, NT64), 256, 0, stream>>>(
        act, W1, out, ypair, meta, pair_tok, pair_sc, nullptr, tok_pos);
    // shared down + gather 4 y_pair rows + coef mix -> out (each element written once)
    down_kernel<false, HSH><<<dim3(DMODEL / 64, S_TOK / 64), 256, 0, stream>>>(
        shact, sdb, out, ypair, nullptr, nullptr, nullptr, coefp, tok_pos);
}

// Round 13
// 360.479 us; speedup vs baseline: 1.7868x; 1.0045x over previous
//
#include <hip/hip_runtime.h>
#include <hip/hip_bf16.h>
#include <stdint.h>

// ---------------- problem dims (fixed by setup_inputs) ----------------
#define S_TOK   2048   // tokens (B*S)
#define DMODEL  2048   // D
#define HEXP    512    // H per expert
#define NEXP    32     // E
#define HSH     1024   // shared hidden
#define NPAIR   (S_TOK * 4)   // 8192 (token,expert) pairs, top_k=4
#define NT128   96            // sum ceil(cnt_e/128) <= 8192/128 + 32
#define NT64    160           // sum ceil(cnt_e/64)  <= 8192/64  + 32

// meta layout (ints): two tile tables (128-row for gateup_e, 64-row for down_e)
#define M128_NT  0
#define M128_TE  1
#define M128_TP0 (1 + NT128)
#define M128_TM  (1 + 2 * NT128)
#define M64_NT   (1 + 3 * NT128)
#define M64_TE   (M64_NT + 1)
#define M64_TP0  (M64_NT + 1 + NT64)
#define M64_TM   (M64_NT + 1 + 2 * NT64)
#define META_SIZE (M64_NT + 1 + 3 * NT64)

typedef short  s16x8 __attribute__((ext_vector_type(8)));
typedef __bf16 b16x8 __attribute__((ext_vector_type(8)));
typedef float  f32x4 __attribute__((ext_vector_type(4)));

__device__ __forceinline__ f32x4 mfma16x16x32(s16x8 a, s16x8 b, f32x4 c) {
    return __builtin_amdgcn_mfma_f32_16x16x32_bf16(
        __builtin_bit_cast(b16x8, a), __builtin_bit_cast(b16x8, b), c, 0, 0, 0);
}

__device__ __forceinline__ unsigned short f2bf(float f) {
    union { float f; unsigned int u; } v; v.f = f;
    unsigned int u = v.u;
    return (unsigned short)((u + 0x7FFFu + ((u >> 16) & 1u)) >> 16);  // RNE
}

__device__ __forceinline__ float bf2f(unsigned short b) {
    union { unsigned int u; float f; } v; v.u = ((unsigned int)b) << 16;
    return v.f;
}

// async global->LDS, 16B per lane. LDS dest is wave-uniform base + lane*16.
__device__ __forceinline__ void gload16(const unsigned short* g, unsigned short* l) {
    __builtin_amdgcn_global_load_lds(
        (const __attribute__((address_space(1))) void*)(uintptr_t)g,
        (__attribute__((address_space(3))) void*)(uintptr_t)l, 16, 0, 0);
}

// ---- LDS bank swizzle for [row][32-short] GEMM tiles (64B rows) ----
// write side: pre-swizzled GLOBAL source granule (gload_lds writes linearly);
// read side XORs fq by the same key(row) = ((row&15)>>1)&3.  [rule #21]
__device__ __forceinline__ int src_col8(int lane) {
    return 8 * ((lane & 3) ^ ((lane >> 3) & 3));
}
__device__ __forceinline__ int frag_ko(int fr, int fq) {
    return 8 * (fq ^ ((fr >> 1) & 3));
}

// ---------------- transpose-convert tile: f32 [K][N] -> bf16 [N][K] ----------------
// LDS [64][84]: 168B rows (42 banks) -> columnar b16 writes are 2-way (free);
// reads via uint2 (8B-aligned at 168B stride). [old 80-pad was 16-way on writes]
__device__ __forceinline__ void tconv_tile(const float* __restrict__ s,
                                           unsigned short* __restrict__ d,
                                           const int K, const int N,
                                           const int k0, const int n0,
                                           unsigned short* pool)   // >= 64*84 shorts
{
    auto T = (unsigned short (*)[84])pool;
    const int tid = threadIdx.x;
    const int n4 = (tid & 15) * 4;
    const int kr = tid >> 4;
#pragma unroll
    for (int i = 0; i < 4; ++i) {
        const int k = kr + i * 16;
        const float4 v = *reinterpret_cast<const float4*>(s + (size_t)(k0 + k) * N + n0 + n4);
        T[n4 + 0][k] = f2bf(v.x);
        T[n4 + 1][k] = f2bf(v.y);
        T[n4 + 2][k] = f2bf(v.z);
        T[n4 + 3][k] = f2bf(v.w);
    }
    __syncthreads();
    const int nw = tid >> 2;
    const int kc = (tid & 3) * 16;
    unsigned short* o = d + (size_t)(n0 + nw) * K + k0 + kc;
#pragma unroll
    for (int j = 0; j < 4; ++j)
        *reinterpret_cast<uint2*>(o + j * 4) =
            *reinterpret_cast<const uint2*>(&T[nw][kc + j * 4]);
}

// ---------------- router: logits, sigmoid, biased top-4, coef softmax ----------------
__global__ __launch_bounds__(256)
void router_kernel(const float* __restrict__ x, const float* __restrict__ gate_w,
                   const float* __restrict__ expert_bias,
                   const float* __restrict__ coef_w, const float* __restrict__ coef_b,
                   int* __restrict__ inds, float* __restrict__ scores,
                   float* __restrict__ coefo)
{
    const int t = blockIdx.x;
    const int tid = threadIdx.x;
    const int lane = tid & 63;
    const int wave = tid >> 6;
    const float* xr = x + (size_t)t * DMODEL;

    float xv[32];
#pragma unroll
    for (int j = 0; j < 32; ++j) xv[j] = xr[lane + 64 * j];

    __shared__ float s_logits[NEXP];
    __shared__ float s_coef[2];

    for (int i = 0; i < 8; ++i) {
        const int e = wave * 8 + i;
        const float* wr = gate_w + (size_t)e * DMODEL;
        float p = 0.f;
#pragma unroll
        for (int j = 0; j < 32; ++j) p += xv[j] * wr[lane + 64 * j];
#pragma unroll
        for (int o = 32; o > 0; o >>= 1) p += __shfl_xor(p, o);
        if (lane == 0) s_logits[e] = p;
    }
    if (wave == 0) {
        for (int c = 0; c < 2; ++c) {
            const float* wr = coef_w + (size_t)c * DMODEL;
            float p = 0.f;
#pragma unroll
            for (int j = 0; j < 32; ++j) p += xv[j] * wr[lane + 64 * j];
#pragma unroll
            for (int o = 32; o > 0; o >>= 1) p += __shfl_xor(p, o);
            if (lane == 0) s_coef[c] = p;
        }
    }
    __syncthreads();
    if (tid == 0) {
        float routing[NEXP], biased[NEXP];
        for (int e = 0; e < NEXP; ++e) {
            const float r = 1.f / (1.f + expf(-s_logits[e]));
            routing[e] = r;
            biased[e] = r + expert_bias[e];
        }
        int sel[4]; float sc[4]; float ssum = 0.f;
        for (int k = 0; k < 4; ++k) {
            int best = 0; float bv = -1e30f;
            for (int e = 0; e < NEXP; ++e)
                if (biased[e] > bv) { bv = biased[e]; best = e; }  // strict > = lax.top_k tie rule
            sel[k] = best; sc[k] = routing[best]; ssum += sc[k];
            biased[best] = -1e30f;
        }
        const float inv = 1.f / (ssum + 1e-20f);
        for (int k = 0; k < 4; ++k) {
            inds[t * 4 + k] = sel[k];
            scores[t * 4 + k] = sc[k] * inv;
        }
        const float l0 = s_coef[0] + coef_b[0];
        const float l1 = s_coef[1] + coef_b[1];
        const float m = fmaxf(l0, l1);
        const float e0 = expf(l0 - m), e1 = expf(l1 - m);
        coefo[t * 2 + 0] = e0 / (e0 + e1);
        coefo[t * 2 + 1] = e1 / (e0 + e1);
    }
}

// ---------------- x: f32 -> bf16 ----------------
__global__ __launch_bounds__(256)
void xcast_kernel(const float* __restrict__ x, unsigned short* __restrict__ xb)
{
    const int i = (blockIdx.x * 256 + threadIdx.x) * 4;
    const float4 v = *reinterpret_cast<const float4*>(x + i);
    ushort4 o;
    o.x = f2bf(v.x); o.y = f2bf(v.y); o.z = f2bf(v.z); o.w = f2bf(v.w);
    *reinterpret_cast<ushort4*>(xb + i) = o;
}

// ---------------- upfront tconv: wg, wu, sg, su, sd in one dispatch ----------------
__global__ __launch_bounds__(256)
void tconv_all_kernel(const float* __restrict__ wg, const float* __restrict__ wu,
                      const float* __restrict__ sg, const float* __restrict__ su,
                      const float* __restrict__ sd,
                      unsigned short* __restrict__ W1, unsigned short* __restrict__ W2,
                      unsigned short* __restrict__ sgb, unsigned short* __restrict__ sub_,
                      unsigned short* __restrict__ sdb)
{
    __shared__ unsigned short pool[64 * 84];
    const int bid = blockIdx.x;
    if (bid < 8192) {               // wg [E][2048][512] -> W1 [E][512][2048]
        const int e = bid >> 8, t = bid & 255;
        tconv_tile(wg + (size_t)e * DMODEL * HEXP, W1 + (size_t)e * HEXP * DMODEL,
                   DMODEL, HEXP, ((t >> 3) & 31) * 64, (t & 7) * 64, pool);
    } else if (bid < 16384) {       // wu -> W2
        const int e = (bid - 8192) >> 8, t = bid & 255;
        tconv_tile(wu + (size_t)e * DMODEL * HEXP, W2 + (size_t)e * HEXP * DMODEL,
                   DMODEL, HEXP, ((t >> 3) & 31) * 64, (t & 7) * 64, pool);
    } else if (bid < 16896) {       // sg [2048][1024] -> sgb [1024][2048]
        const int t = bid - 16384;
        tconv_tile(sg, sgb, DMODEL, HSH, (t >> 4) * 64, (t & 15) * 64, pool);
    } else if (bid < 17408) {       // su -> sub_
        const int t = bid - 16896;
        tconv_tile(su, sub_, DMODEL, HSH, (t >> 4) * 64, (t & 15) * 64, pool);
    } else {                        // sd [1024][2048] -> sdb [2048][1024]
        const int t = bid - 17408;
        tconv_tile(sd, sdb, HSH, DMODEL, (t >> 5) * 64, (t & 31) * 64, pool);
    }
}

// ---------------- wd tconv (after gateups; W1 is dead, reuse it) ----------------
__global__ __launch_bounds__(256)
void tconv_wd_kernel(const float* __restrict__ wd, unsigned short* __restrict__ wdb)
{
    __shared__ unsigned short pool[64 * 84];
    const int e = blockIdx.x >> 8, t = blockIdx.x & 255;
    tconv_tile(wd + (size_t)e * HEXP * DMODEL, wdb + (size_t)e * DMODEL * HEXP,
               HEXP, DMODEL, (t >> 5) * 64, (t & 31) * 64, pool);
}

// ---------------- grouping: pair lists + BOTH tile tables + token->pos map ----
__global__ __launch_bounds__(1024)
void group_kernel(const int* __restrict__ inds, const float* __restrict__ scores,
                  int* __restrict__ meta, int* __restrict__ pair_token,
                  float* __restrict__ pair_score, int* __restrict__ tok_pos)
{
    __shared__ int cnt[NEXP];
    __shared__ int off_s[NEXP];
    __shared__ int cur[NEXP];
    const int tid = threadIdx.x;
    if (tid < NEXP) cnt[tid] = 0;
    __syncthreads();
    for (int i = tid; i < NPAIR; i += 1024) atomicAdd(&cnt[inds[i]], 1);
    __syncthreads();
    if (tid == 0) {
        int run = 0, nt1 = 0, nt2 = 0;
        for (int e = 0; e < NEXP; ++e) {
            off_s[e] = run;
            const int c = cnt[e];
            for (int m0 = 0; m0 < c; m0 += 128) {
                meta[M128_TE + nt1] = e;
                meta[M128_TP0 + nt1] = run + m0;
                meta[M128_TM + nt1] = (c - m0 < 128) ? (c - m0) : 128;
                ++nt1;
            }
            for (int m0 = 0; m0 < c; m0 += 64) {
                meta[M64_TE + nt2] = e;
                meta[M64_TP0 + nt2] = run + m0;
                meta[M64_TM + nt2] = (c - m0 < 64) ? (c - m0) : 64;
                ++nt2;
            }
            run += c;
        }
        meta[M128_NT] = nt1;
        meta[M64_NT] = nt2;
    }
    __syncthreads();
    if (tid < NEXP) cur[tid] = off_s[tid];
    __syncthreads();
    for (int i = tid; i < NPAIR; i += 1024) {
        const int e = inds[i];
        const int pos = atomicAdd(&cur[e], 1);
        pair_token[pos] = i >> 2;
        pair_score[pos] = scores[i];
        tok_pos[i] = pos;
    }
}

// ---------------- fused gate+up: expert (BM=128) + shared (BM=64) in one dispatch --
// bid < 8*NT128            : expert GEMM tile (tt = bid>>3, n-tile = bid&7)
// bid in [8*NT128, +512)   : shared GEMM tile (32 m-tiles x 16 n-tiles)
__global__ __launch_bounds__(256, 4)
void gufused_kernel(const unsigned short* __restrict__ xb,
                    const unsigned short* __restrict__ W1,
                    const unsigned short* __restrict__ W2,
                    unsigned short* __restrict__ act,
                    const int* __restrict__ meta, const int* __restrict__ pair_token,
                    const unsigned short* __restrict__ sgb,
                    const unsigned short* __restrict__ sub_,
                    unsigned short* __restrict__ shact)
{
    __shared__ unsigned short pool[16384];   // 32 KB
    const int bid = blockIdx.x;
    const int tid = threadIdx.x;
    const int lane = tid & 63;
    const int wave = tid >> 6;
    const int fr = lane & 15, fq = lane >> 4;
    const int ko = frag_ko(fr, fq);
    const int sub = lane >> 2;
    const int col8 = src_col8(lane);
    const f32x4 zero4 = {0.f, 0.f, 0.f, 0.f};

    if (bid < 8 * NT128) {   // ======== expert gate+up, BM=128 ========
        constexpr int NT = DMODEL / 32;
        constexpr int NB = HEXP;
        auto Al  = (unsigned short (*)[128][32])(pool);
        auto Bgl = (unsigned short (*)[64][32])(pool + 8192);
        auto Bul = (unsigned short (*)[64][32])(pool + 12288);

        const int tt = bid >> 3;
        if (tt >= meta[M128_NT]) return;
        const int e = meta[M128_TE + tt];
        const int p0 = meta[M128_TP0 + tt];
        const int mval = meta[M128_TM + tt];
        const size_t eoff = (size_t)e * NB * DMODEL;
        const unsigned short* Bg = W1 + eoff;
        const unsigned short* Bu = W2 + eoff;
        const int n0 = (bid & 7) * 64;

        const int arow0 = wave * 32 + sub;
        int q0 = p0 + arow0; if (q0 > NPAIR - 1) q0 = NPAIR - 1;
        int q1 = p0 + arow0 + 16; if (q1 > NPAIR - 1) q1 = NPAIR - 1;
        const unsigned short* asrc0 = xb + (size_t)pair_token[q0] * DMODEL + col8;
        const unsigned short* asrc1 = xb + (size_t)pair_token[q1] * DMODEL + col8;
        const int brow = wave * 16 + sub;
        const unsigned short* gsrc = Bg + (size_t)(n0 + brow) * DMODEL + col8;
        const unsigned short* usrc = Bu + (size_t)(n0 + brow) * DMODEL + col8;

        auto stage = [&](int buf, int k0) {
            gload16(asrc0 + k0, &Al[buf][wave * 32][0]);
            gload16(asrc1 + k0, &Al[buf][wave * 32 + 16][0]);
            gload16(gsrc + k0, &Bgl[buf][wave * 16][0]);
            gload16(usrc + k0, &Bul[buf][wave * 16][0]);
        };

        const int wm = wave >> 1, wn = wave & 1;
        f32x4 hacc[4][2], uacc[4][2];
#pragma unroll
        for (int m = 0; m < 4; ++m)
#pragma unroll
            for (int n = 0; n < 2; ++n) { hacc[m][n] = zero4; uacc[m][n] = zero4; }

        auto compute = [&](int buf) {
            s16x8 af[4], bg[2], bu[2];
#pragma unroll
            for (int m = 0; m < 4; ++m)
                af[m] = *reinterpret_cast<const s16x8*>(&Al[buf][wm * 64 + m * 16 + fr][ko]);
#pragma unroll
            for (int n = 0; n < 2; ++n) {
                bg[n] = *reinterpret_cast<const s16x8*>(&Bgl[buf][wn * 32 + n * 16 + fr][ko]);
                bu[n] = *reinterpret_cast<const s16x8*>(&Bul[buf][wn * 32 + n * 16 + fr][ko]);
            }
#pragma unroll
            for (int m = 0; m < 4; ++m)
#pragma unroll
                for (int n = 0; n < 2; ++n) {
                    hacc[m][n] = mfma16x16x32(af[m], bg[n], hacc[m][n]);
                    uacc[m][n] = mfma16x16x32(af[m], bu[n], uacc[m][n]);
                }
        };

        stage(0, 0);
        __syncthreads();
#pragma unroll 1
        for (int t = 0; t < NT; ++t) {
            const int cur = t & 1;
            if (t + 1 < NT) stage(cur ^ 1, (t + 1) * 32);
            compute(cur);
            __syncthreads();
        }

#pragma unroll
        for (int m = 0; m < 4; ++m)
#pragma unroll
            for (int n = 0; n < 2; ++n) {
                const int col = n0 + wn * 32 + n * 16 + fr;
#pragma unroll
                for (int r = 0; r < 4; ++r) {
                    const int rt = wm * 64 + m * 16 + fq * 4 + r;
                    if (rt < mval) {
                        const float hv = hacc[m][n][r];
                        const float a = hv / (1.f + __expf(-hv)) * uacc[m][n][r];
                        act[(size_t)(p0 + rt) * NB + col] = f2bf(a);
                    }
                }
            }
    } else {                 // ======== shared gate+up, BM=64 ========
        constexpr int NT = DMODEL / 32;
        constexpr int NB = HSH;
        auto Al  = (unsigned short (*)[64][32])(pool);
        auto Bgl = (unsigned short (*)[64][32])(pool + 4096);
        auto Bul = (unsigned short (*)[64][32])(pool + 8192);

        const int idx = bid - 8 * NT128;
        const int p0 = (idx >> 4) * 64;
        const int n0 = (idx & 15) * 64;

        const int arow = wave * 16 + sub;
        const unsigned short* asrc = xb + (size_t)(p0 + arow) * DMODEL + col8;
        const unsigned short* gsrc = sgb + (size_t)(n0 + arow) * DMODEL + col8;
        const unsigned short* usrc = sub_ + (size_t)(n0 + arow) * DMODEL + col8;

        auto stage = [&](int buf, int k0) {
            gload16(asrc + k0, &Al[buf][wave * 16][0]);
            gload16(gsrc + k0, &Bgl[buf][wave * 16][0]);
            gload16(usrc + k0, &Bul[buf][wave * 16][0]);
        };

        const int wm = wave >> 1, wn = wave & 1;
        f32x4 hacc[2][2], uacc[2][2];
#pragma unroll
        for (int m = 0; m < 2; ++m)
#pragma unroll
            for (int n = 0; n < 2; ++n) { hacc[m][n] = zero4; uacc[m][n] = zero4; }

        auto compute = [&](int buf) {
            s16x8 af[2], bg[2], bu[2];
#pragma unroll
            for (int m = 0; m < 2; ++m)
                af[m] = *reinterpret_cast<const s16x8*>(&Al[buf][wm * 32 + m * 16 + fr][ko]);
#pragma unroll
            for (int n = 0; n < 2; ++n) {
                bg[n] = *reinterpret_cast<const s16x8*>(&Bgl[buf][wn * 32 + n * 16 + fr][ko]);
                bu[n] = *reinterpret_cast<const s16x8*>(&Bul[buf][wn * 32 + n * 16 + fr][ko]);
            }
#pragma unroll
            for (int m = 0; m < 2; ++m)
#pragma unroll
                for (int n = 0; n < 2; ++n) {
                    hacc[m][n] = mfma16x16x32(af[m], bg[n], hacc[m][n]);
                    uacc[m][n] = mfma16x16x32(af[m], bu[n], uacc[m][n]);
                }
        };

        stage(0, 0);
        __syncthreads();
#pragma unroll 1
        for (int t = 0; t < NT; ++t) {
            const int cur = t & 1;
            if (t + 1 < NT) stage(cur ^ 1, (t + 1) * 32);
            compute(cur);
            __syncthreads();
        }

#pragma unroll
        for (int m = 0; m < 2; ++m)
#pragma unroll
            for (int n = 0; n < 2; ++n) {
                const int col = n0 + wn * 32 + n * 16 + fr;
#pragma unroll
                for (int r = 0; r < 4; ++r) {
                    const int rt = wm * 32 + m * 16 + fq * 4 + r;
                    const float hv = hacc[m][n][r];
                    const float a = hv / (1.f + __expf(-hv)) * uacc[m][n][r];
                    shact[(size_t)(p0 + rt) * NB + col] = f2bf(a);
                }
            }
    }
}

// ---------------- fused down: expert (KA=512 -> ypair) + shared (KA=1024 -> sdown) -
__global__ __launch_bounds__(256, 4)
void downfused_kernel(const unsigned short* __restrict__ act,
                      const unsigned short* __restrict__ shact,
                      const unsigned short* __restrict__ wdb,
                      const unsigned short* __restrict__ sdb,
                      unsigned short* __restrict__ ypair,
                      float* __restrict__ sdown,
                      const int* __restrict__ meta,
                      const float* __restrict__ pair_score)
{
    __shared__ unsigned short Al[2][64][32];
    __shared__ unsigned short Bl[2][64][32];
    const int bid = blockIdx.x;
    const int tid = threadIdx.x;
    const int lane = tid & 63;
    const int wave = tid >> 6;
    const int fr = lane & 15, fq = lane >> 4;
    const int ko = frag_ko(fr, fq);
    const int sub = lane >> 2;
    const int col8 = src_col8(lane);
    const int wm = wave >> 1, wn = wave & 1;
    const f32x4 zero4 = {0.f, 0.f, 0.f, 0.f};

    const bool EXPERT = bid < 32 * NT64;
    int p0, mval, n0, KA;
    const unsigned short *Asrc, *Bd;
    if (EXPERT) {
        const int tt = bid >> 5;
        if (tt >= meta[M64_NT]) return;
        const int e = meta[M64_TE + tt];
        p0 = meta[M64_TP0 + tt];
        mval = meta[M64_TM + tt];
        n0 = (bid & 31) * 64;
        KA = HEXP;
        Asrc = act;
        Bd = wdb + (size_t)e * DMODEL * HEXP;
    } else {
        const int idx = bid - 32 * NT64;
        p0 = (idx >> 5) * 64;
        mval = 64;
        n0 = (idx & 31) * 64;
        KA = HSH;
        Asrc = shact;
        Bd = sdb;
    }
    const int NT = KA / 32;

    const int arow = wave * 16 + sub;
    int ar = p0 + arow;
    if (EXPERT && ar > NPAIR - 1) ar = NPAIR - 1;
    const unsigned short* asrc = Asrc + (size_t)ar * KA + col8;
    const unsigned short* bsrc = Bd + (size_t)(n0 + arow) * KA + col8;

    auto stage = [&](int buf, int k0) {
        gload16(asrc + k0, &Al[buf][wave * 16][0]);
        gload16(bsrc + k0, &Bl[buf][wave * 16][0]);
    };

    f32x4 acc[2][2];
#pragma unroll
    for (int m = 0; m < 2; ++m)
#pragma unroll
        for (int n = 0; n < 2; ++n) acc[m][n] = zero4;

    auto compute = [&](int buf) {
        s16x8 af[2], bf[2];
#pragma unroll
        for (int m = 0; m < 2; ++m)
            af[m] = *reinterpret_cast<const s16x8*>(&Al[buf][wm * 32 + m * 16 + fr][ko]);
#pragma unroll
        for (int n = 0; n < 2; ++n)
            bf[n] = *reinterpret_cast<const s16x8*>(&Bl[buf][wn * 32 + n * 16 + fr][ko]);
#pragma unroll
        for (int m = 0; m < 2; ++m)
#pragma unroll
            for (int n = 0; n < 2; ++n)
                acc[m][n] = mfma16x16x32(af[m], bf[n], acc[m][n]);
    };

    stage(0, 0);
    __syncthreads();
#pragma unroll 1
    for (int t = 0; t < NT; ++t) {
        const int cur = t & 1;
        if (t + 1 < NT) stage(cur ^ 1, (t + 1) * 32);
        compute(cur);
        __syncthreads();
    }

#pragma unroll
    for (int m = 0; m < 2; ++m)
#pragma unroll
        for (int n = 0; n < 2; ++n) {
            const int col = n0 + wn * 32 + n * 16 + fr;
#pragma unroll
            for (int r = 0; r < 4; ++r) {
                const int rt = wm * 32 + m * 16 + fq * 4 + r;
                if (rt < mval) {
                    if (EXPERT) {
                        const int p = p0 + rt;
                        ypair[(size_t)p * DMODEL + col] = f2bf(acc[m][n][r] * pair_score[p]);
                    } else {
                        sdown[(size_t)(p0 + rt) * DMODEL + col] = acc[m][n][r];
                    }
                }
            }
        }
}

// ---------------- final: out = (sum_k ypair[pos_k])*c0 + sdown*c1 ----------------
__global__ __launch_bounds__(256)
void final_kernel(const unsigned short* __restrict__ ypair,
                  const float* __restrict__ sdown,
                  const float* __restrict__ coef, const int* __restrict__ tok_pos,
                  float* __restrict__ out)
{
    const int row = blockIdx.x;
    const int col = threadIdx.x * 8;
    float acc[8] = {0.f, 0.f, 0.f, 0.f, 0.f, 0.f, 0.f, 0.f};
#pragma unroll
    for (int k = 0; k < 4; ++k) {
        const int pos = tok_pos[row * 4 + k];
        const uint4 v = *reinterpret_cast<const uint4*>(ypair + (size_t)pos * DMODEL + col);
        const unsigned short* u = reinterpret_cast<const unsigned short*>(&v);
#pragma unroll
        for (int j = 0; j < 8; ++j) acc[j] += bf2f(u[j]);
    }
    const float c0 = coef[row * 2 + 0];
    const float c1 = coef[row * 2 + 1];
    const float* sd = sdown + (size_t)row * DMODEL + col;
    const float4 s0 = *reinterpret_cast<const float4*>(sd);
    const float4 s1 = *reinterpret_cast<const float4*>(sd + 4);
    float4 o0, o1;
    o0.x = acc[0] * c0 + s0.x * c1; o0.y = acc[1] * c0 + s0.y * c1;
    o0.z = acc[2] * c0 + s0.z * c1; o0.w = acc[3] * c0 + s0.w * c1;
    o1.x = acc[4] * c0 + s1.x * c1; o1.y = acc[5] * c0 + s1.y * c1;
    o1.z = acc[6] * c0 + s1.z * c1; o1.w = acc[7] * c0 + s1.w * c1;
    float* op = out + (size_t)row * DMODEL + col;
    *reinterpret_cast<float4*>(op) = o0;
    *reinterpret_cast<float4*>(op + 4) = o1;
}

// ---------------- launch ----------------
extern "C" void kernel_launch(void* const* d_in, const int* in_sizes, int n_in,
                              void* d_out, int out_size, void* d_ws, size_t ws_size,
                              hipStream_t stream)
{
    const float* x           = (const float*)d_in[0];
    const float* gate_w      = (const float*)d_in[1];
    const float* expert_bias = (const float*)d_in[2];
    const float* wg          = (const float*)d_in[3];
    const float* wu          = (const float*)d_in[4];
    const float* wd          = (const float*)d_in[5];
    const float* sg          = (const float*)d_in[6];
    const float* su          = (const float*)d_in[7];
    const float* sd          = (const float*)d_in[8];
    const float* coef_w      = (const float*)d_in[9];
    const float* coef_b      = (const float*)d_in[10];
    float* out = (float*)d_out;

    char* ws = (char*)d_ws;
    size_t off = 0;
    auto take = [&](size_t bytes) {
        char* p = ws + off;
        off = (off + bytes + 255) & ~(size_t)255;
        return p;
    };
    int*   inds     = (int*)  take((size_t)S_TOK * 4 * sizeof(int));
    float* scores   = (float*)take((size_t)S_TOK * 4 * sizeof(float));
    float* coefp    = (float*)take((size_t)S_TOK * 2 * sizeof(float));
    int*   meta     = (int*)  take((size_t)META_SIZE * sizeof(int));
    int*   pair_tok = (int*)  take((size_t)NPAIR * sizeof(int));
    float* pair_sc  = (float*)take((size_t)NPAIR * sizeof(float));
    int*   tok_pos  = (int*)  take((size_t)NPAIR * sizeof(int));
    unsigned short* xb    = (unsigned short*)take((size_t)S_TOK * DMODEL * 2);
    unsigned short* act   = (unsigned short*)take((size_t)NPAIR * HEXP * 2);
    unsigned short* shact = (unsigned short*)take((size_t)S_TOK * HSH * 2);
    unsigned short* ypair = (unsigned short*)take((size_t)NPAIR * DMODEL * 2);  // 33.5MB
    float*          sdown = (float*)take((size_t)S_TOK * DMODEL * 4);           // 16.8MB
    unsigned short* sgb   = (unsigned short*)take((size_t)HSH * DMODEL * 2);
    unsigned short* sub_  = (unsigned short*)take((size_t)HSH * DMODEL * 2);
    unsigned short* sdb   = (unsigned short*)take((size_t)DMODEL * HSH * 2);
    unsigned short* W1    = (unsigned short*)take((size_t)NEXP * DMODEL * HEXP * 2); // 64MB
    unsigned short* W2    = (unsigned short*)take((size_t)NEXP * DMODEL * HEXP * 2); // 64MB
    (void)ws_size; (void)in_sizes; (void)n_in; (void)out_size;

    router_kernel<<<S_TOK, 256, 0, stream>>>(x, gate_w, expert_bias, coef_w, coef_b,
                                             inds, scores, coefp);
    xcast_kernel<<<(S_TOK * DMODEL / 4) / 256, 256, 0, stream>>>(x, xb);
    group_kernel<<<1, 1024, 0, stream>>>(inds, scores, meta, pair_tok, pair_sc, tok_pos);

    // all pre-GEMM weight conversions in ONE dispatch (17736 blocks, HBM-streaming)
    tconv_all_kernel<<<17920, 256, 0, stream>>>(wg, wu, sg, su, sd,
                                                W1, W2, sgb, sub_, sdb);

    // fused gate+up: expert (768 tiles) + shared (512 tiles) fill the grid together
    gufused_kernel<<<8 * NT128 + 512, 256, 0, stream>>>(
        xb, W1, W2, act, meta, pair_tok, sgb, sub_, shact);

    // wd -> bf16 [E][D][H] into W1 (dead after gufused)
    tconv_wd_kernel<<<NEXP * 256, 256, 0, stream>>>(wd, W1);

    // fused down: expert (-> ypair, scaled) + shared (-> sdown f32)
    downfused_kernel<<<32 * NT64 + 1024, 256, 0, stream>>>(
        act, shact, W1, sdb, ypair, sdown, meta, pair_sc);

    // final combine (each out element written exactly once)
    final_kernel<<<S_TOK, 256, 0, stream>>>(ypair, sdown, coefp, tok_pos, out);
}

// Round 14
// 348.838 us; speedup vs baseline: 1.8464x; 1.0334x over previous
//
#include <hip/hip_runtime.h>
#include <hip/hip_bf16.h>
#include <stdint.h>

// ---------------- problem dims (fixed by setup_inputs) ----------------
#define S_TOK   2048   // tokens (B*S)
#define DMODEL  2048   // D
#define HEXP    512    // H per expert
#define NEXP    32     // E
#define HSH     1024   // shared hidden
#define NPAIR   (S_TOK * 4)   // 8192 (token,expert) pairs, top_k=4
#define NT128   96            // sum ceil(cnt_e/128) <= 8192/128 + 32

// meta layout (ints): 128-row tile table
#define M128_NT  0
#define M128_TE  1
#define M128_TP0 (1 + NT128)
#define M128_TM  (1 + 2 * NT128)
#define META_SIZE (1 + 3 * NT128)

typedef short  s16x8 __attribute__((ext_vector_type(8)));
typedef __bf16 b16x8 __attribute__((ext_vector_type(8)));
typedef float  f32x4 __attribute__((ext_vector_type(4)));

__device__ __forceinline__ f32x4 mfma16x16x32(s16x8 a, s16x8 b, f32x4 c) {
    return __builtin_amdgcn_mfma_f32_16x16x32_bf16(
        __builtin_bit_cast(b16x8, a), __builtin_bit_cast(b16x8, b), c, 0, 0, 0);
}

__device__ __forceinline__ unsigned short f2bf(float f) {
    union { float f; unsigned int u; } v; v.f = f;
    unsigned int u = v.u;
    return (unsigned short)((u + 0x7FFFu + ((u >> 16) & 1u)) >> 16);  // RNE
}

__device__ __forceinline__ float bf2f(unsigned short b) {
    union { unsigned int u; float f; } v; v.u = ((unsigned int)b) << 16;
    return v.f;
}

// async global->LDS, 16B per lane. LDS dest is wave-uniform base + lane*16.
__device__ __forceinline__ void gload16(const unsigned short* g, unsigned short* l) {
    __builtin_amdgcn_global_load_lds(
        (const __attribute__((address_space(1))) void*)(uintptr_t)g,
        (__attribute__((address_space(3))) void*)(uintptr_t)l, 16, 0, 0);
}

// ---- LDS bank swizzle for [row][32-short] GEMM tiles (64B rows) ----
// write side: pre-swizzled GLOBAL source granule (gload_lds writes linearly);
// read side XORs fq by the same key(row) = ((row&15)>>1)&3.  [rule #21]
__device__ __forceinline__ int src_col8(int lane) {
    return 8 * ((lane & 3) ^ ((lane >> 3) & 3));
}
__device__ __forceinline__ int frag_ko(int fr, int fq) {
    return 8 * (fq ^ ((fr >> 1) & 3));
}

// ---------------- transpose-convert tile: f32 [K][N] -> bf16 [N][K] ----------------
__device__ __forceinline__ void tconv_tile(const float* __restrict__ s,
                                           unsigned short* __restrict__ d,
                                           const int K, const int N,
                                           const int k0, const int n0,
                                           unsigned short* pool)   // >= 64*84 shorts
{
    auto T = (unsigned short (*)[84])pool;
    const int tid = threadIdx.x;
    const int n4 = (tid & 15) * 4;
    const int kr = tid >> 4;
#pragma unroll
    for (int i = 0; i < 4; ++i) {
        const int k = kr + i * 16;
        const float4 v = *reinterpret_cast<const float4*>(s + (size_t)(k0 + k) * N + n0 + n4);
        T[n4 + 0][k] = f2bf(v.x);
        T[n4 + 1][k] = f2bf(v.y);
        T[n4 + 2][k] = f2bf(v.z);
        T[n4 + 3][k] = f2bf(v.w);
    }
    __syncthreads();
    const int nw = tid >> 2;
    const int kc = (tid & 3) * 16;
    unsigned short* o = d + (size_t)(n0 + nw) * K + k0 + kc;
#pragma unroll
    for (int j = 0; j < 4; ++j)
        *reinterpret_cast<uint2*>(o + j * 4) =
            *reinterpret_cast<const uint2*>(&T[nw][kc + j * 4]);
}

// ---------------- router: logits, sigmoid, biased top-4, coef softmax ----------------
__global__ __launch_bounds__(256)
void router_kernel(const float* __restrict__ x, const float* __restrict__ gate_w,
                   const float* __restrict__ expert_bias,
                   const float* __restrict__ coef_w, const float* __restrict__ coef_b,
                   int* __restrict__ inds, float* __restrict__ scores,
                   float* __restrict__ coefo)
{
    const int t = blockIdx.x;
    const int tid = threadIdx.x;
    const int lane = tid & 63;
    const int wave = tid >> 6;
    const float* xr = x + (size_t)t * DMODEL;

    float xv[32];
#pragma unroll
    for (int j = 0; j < 32; ++j) xv[j] = xr[lane + 64 * j];

    __shared__ float s_logits[NEXP];
    __shared__ float s_coef[2];

    for (int i = 0; i < 8; ++i) {
        const int e = wave * 8 + i;
        const float* wr = gate_w + (size_t)e * DMODEL;
        float p = 0.f;
#pragma unroll
        for (int j = 0; j < 32; ++j) p += xv[j] * wr[lane + 64 * j];
#pragma unroll
        for (int o = 32; o > 0; o >>= 1) p += __shfl_xor(p, o);
        if (lane == 0) s_logits[e] = p;
    }
    if (wave == 0) {
        for (int c = 0; c < 2; ++c) {
            const float* wr = coef_w + (size_t)c * DMODEL;
            float p = 0.f;
#pragma unroll
            for (int j = 0; j < 32; ++j) p += xv[j] * wr[lane + 64 * j];
#pragma unroll
            for (int o = 32; o > 0; o >>= 1) p += __shfl_xor(p, o);
            if (lane == 0) s_coef[c] = p;
        }
    }
    __syncthreads();
    if (tid == 0) {
        float routing[NEXP], biased[NEXP];
        for (int e = 0; e < NEXP; ++e) {
            const float r = 1.f / (1.f + expf(-s_logits[e]));
            routing[e] = r;
            biased[e] = r + expert_bias[e];
        }
        int sel[4]; float sc[4]; float ssum = 0.f;
        for (int k = 0; k < 4; ++k) {
            int best = 0; float bv = -1e30f;
            for (int e = 0; e < NEXP; ++e)
                if (biased[e] > bv) { bv = biased[e]; best = e; }  // strict > = lax.top_k tie rule
            sel[k] = best; sc[k] = routing[best]; ssum += sc[k];
            biased[best] = -1e30f;
        }
        const float inv = 1.f / (ssum + 1e-20f);
        for (int k = 0; k < 4; ++k) {
            inds[t * 4 + k] = sel[k];
            scores[t * 4 + k] = sc[k] * inv;
        }
        const float l0 = s_coef[0] + coef_b[0];
        const float l1 = s_coef[1] + coef_b[1];
        const float m = fmaxf(l0, l1);
        const float e0 = expf(l0 - m), e1 = expf(l1 - m);
        coefo[t * 2 + 0] = e0 / (e0 + e1);
        coefo[t * 2 + 1] = e1 / (e0 + e1);
    }
}

// ---------------- x: f32 -> bf16 ----------------
__global__ __launch_bounds__(256)
void xcast_kernel(const float* __restrict__ x, unsigned short* __restrict__ xb)
{
    const int i = (blockIdx.x * 256 + threadIdx.x) * 4;
    const float4 v = *reinterpret_cast<const float4*>(x + i);
    ushort4 o;
    o.x = f2bf(v.x); o.y = f2bf(v.y); o.z = f2bf(v.z); o.w = f2bf(v.w);
    *reinterpret_cast<ushort4*>(xb + i) = o;
}

// ---------------- upfront tconv: wg, wu, sg, su, sd in one dispatch ----------------
__global__ __launch_bounds__(256)
void tconv_all_kernel(const float* __restrict__ wg, const float* __restrict__ wu,
                      const float* __restrict__ sg, const float* __restrict__ su,
                      const float* __restrict__ sd,
                      unsigned short* __restrict__ W1, unsigned short* __restrict__ W2,
                      unsigned short* __restrict__ sgb, unsigned short* __restrict__ sub_,
                      unsigned short* __restrict__ sdb)
{
    __shared__ unsigned short pool[64 * 84];
    const int bid = blockIdx.x;
    if (bid < 8192) {               // wg [E][2048][512] -> W1 [E][512][2048]
        const int e = bid >> 8, t = bid & 255;
        tconv_tile(wg + (size_t)e * DMODEL * HEXP, W1 + (size_t)e * HEXP * DMODEL,
                   DMODEL, HEXP, ((t >> 3) & 31) * 64, (t & 7) * 64, pool);
    } else if (bid < 16384) {       // wu -> W2
        const int e = (bid - 8192) >> 8, t = bid & 255;
        tconv_tile(wu + (size_t)e * DMODEL * HEXP, W2 + (size_t)e * HEXP * DMODEL,
                   DMODEL, HEXP, ((t >> 3) & 31) * 64, (t & 7) * 64, pool);
    } else if (bid < 16896) {       // sg [2048][1024] -> sgb [1024][2048]
        const int t = bid - 16384;
        tconv_tile(sg, sgb, DMODEL, HSH, (t >> 4) * 64, (t & 15) * 64, pool);
    } else if (bid < 17408) {       // su -> sub_
        const int t = bid - 16896;
        tconv_tile(su, sub_, DMODEL, HSH, (t >> 4) * 64, (t & 15) * 64, pool);
    } else {                        // sd [1024][2048] -> sdb [2048][1024]
        const int t = bid - 17408;
        tconv_tile(sd, sdb, HSH, DMODEL, (t >> 5) * 64, (t & 31) * 64, pool);
    }
}

// ---------------- wd tconv (after gateups; W1 is dead, reuse it) ----------------
__global__ __launch_bounds__(256)
void tconv_wd_kernel(const float* __restrict__ wd, unsigned short* __restrict__ wdb)
{
    __shared__ unsigned short pool[64 * 84];
    const int e = blockIdx.x >> 8, t = blockIdx.x & 255;
    tconv_tile(wd + (size_t)e * HEXP * DMODEL, wdb + (size_t)e * DMODEL * HEXP,
               HEXP, DMODEL, (t >> 5) * 64, (t & 31) * 64, pool);
}

// ---------------- grouping: pair lists + 128-row tile table + token->pos map ----
__global__ __launch_bounds__(1024)
void group_kernel(const int* __restrict__ inds, const float* __restrict__ scores,
                  int* __restrict__ meta, int* __restrict__ pair_token,
                  float* __restrict__ pair_score, int* __restrict__ tok_pos)
{
    __shared__ int cnt[NEXP];
    __shared__ int off_s[NEXP];
    __shared__ int cur[NEXP];
    const int tid = threadIdx.x;
    if (tid < NEXP) cnt[tid] = 0;
    __syncthreads();
    for (int i = tid; i < NPAIR; i += 1024) atomicAdd(&cnt[inds[i]], 1);
    __syncthreads();
    if (tid == 0) {
        int run = 0, nt1 = 0;
        for (int e = 0; e < NEXP; ++e) {
            off_s[e] = run;
            const int c = cnt[e];
            for (int m0 = 0; m0 < c; m0 += 128) {
                meta[M128_TE + nt1] = e;
                meta[M128_TP0 + nt1] = run + m0;
                meta[M128_TM + nt1] = (c - m0 < 128) ? (c - m0) : 128;
                ++nt1;
            }
            run += c;
        }
        meta[M128_NT] = nt1;
    }
    __syncthreads();
    if (tid < NEXP) cur[tid] = off_s[tid];
    __syncthreads();
    for (int i = tid; i < NPAIR; i += 1024) {
        const int e = inds[i];
        const int pos = atomicAdd(&cur[e], 1);
        pair_token[pos] = i >> 2;
        pair_score[pos] = scores[i];
        tok_pos[i] = pos;
    }
}

// ---------------- gate/up GEMM, m97 shape: 128x128 single-matrix blocks -----------
// bid < 8*NT128 : expert tile. tt=bid>>3; r=bid&7: mat=r>>2, n0=(r&3)*128.
// else          : shared tile. idx: mat=idx&1, n0=((idx>>1)&7)*128, p0=(idx>>4)*128.
// 64 MFMA/block/K-step, 8 b128 reads/wave/step -- the proven m97 ratio.
__global__ __launch_bounds__(256, 3)
void gu128_kernel(const unsigned short* __restrict__ xb,
                  const unsigned short* __restrict__ W1,
                  const unsigned short* __restrict__ W2,
                  const int* __restrict__ meta, const int* __restrict__ pair_token,
                  const unsigned short* __restrict__ sgb,
                  const unsigned short* __restrict__ sub_,
                  unsigned short* __restrict__ hexp, unsigned short* __restrict__ uexp,
                  unsigned short* __restrict__ shh, unsigned short* __restrict__ shu)
{
    constexpr int NT = DMODEL / 32;
    __shared__ unsigned short Al[2][128][32];
    __shared__ unsigned short Bl[2][128][32];

    const int bid = blockIdx.x;
    const int tid = threadIdx.x;
    const int lane = tid & 63;
    const int wave = tid >> 6;
    const int fr = lane & 15, fq = lane >> 4;
    const int ko = frag_ko(fr, fq);
    const int sub = lane >> 2;
    const int col8 = src_col8(lane);
    const int wm = wave >> 1, wn = wave & 1;
    const f32x4 zero4 = {0.f, 0.f, 0.f, 0.f};

    const bool EXPERT = bid < 8 * NT128;
    int p0, mval, n0, NB;
    const unsigned short* B;
    unsigned short* obuf;
    int tok0, tok1;
    const int arow0 = wave * 32 + sub;
    if (EXPERT) {
        const int tt = bid >> 3;
        if (tt >= meta[M128_NT]) return;
        const int e = meta[M128_TE + tt];
        p0 = meta[M128_TP0 + tt];
        mval = meta[M128_TM + tt];
        const int r = bid & 7;
        const int mat = r >> 2;
        n0 = (r & 3) * 128;
        NB = HEXP;
        B = (mat ? W2 : W1) + (size_t)e * HEXP * DMODEL;
        obuf = mat ? uexp : hexp;
        int q0 = p0 + arow0;      if (q0 > NPAIR - 1) q0 = NPAIR - 1;
        int q1 = p0 + arow0 + 16; if (q1 > NPAIR - 1) q1 = NPAIR - 1;
        tok0 = pair_token[q0];
        tok1 = pair_token[q1];
    } else {
        const int idx = bid - 8 * NT128;   // 256 blocks: 16m x 8n x 2mats
        const int mat = idx & 1;
        n0 = ((idx >> 1) & 7) * 128;
        p0 = (idx >> 4) * 128;
        mval = 128;
        NB = HSH;
        B = mat ? sub_ : sgb;
        obuf = mat ? shu : shh;
        tok0 = p0 + arow0;
        tok1 = p0 + arow0 + 16;
    }

    const unsigned short* asrc0 = xb + (size_t)tok0 * DMODEL + col8;
    const unsigned short* asrc1 = xb + (size_t)tok1 * DMODEL + col8;
    const unsigned short* bsrc0 = B + (size_t)(n0 + arow0) * DMODEL + col8;
    const unsigned short* bsrc1 = B + (size_t)(n0 + arow0 + 16) * DMODEL + col8;

    auto stage = [&](int buf, int k0) {
        gload16(asrc0 + k0, &Al[buf][wave * 32][0]);
        gload16(asrc1 + k0, &Al[buf][wave * 32 + 16][0]);
        gload16(bsrc0 + k0, &Bl[buf][wave * 32][0]);
        gload16(bsrc1 + k0, &Bl[buf][wave * 32 + 16][0]);
    };

    f32x4 acc[4][4];
#pragma unroll
    for (int m = 0; m < 4; ++m)
#pragma unroll
        for (int n = 0; n < 4; ++n) acc[m][n] = zero4;

    auto compute = [&](int buf) {
        s16x8 af[4], bf[4];
#pragma unroll
        for (int m = 0; m < 4; ++m)
            af[m] = *reinterpret_cast<const s16x8*>(&Al[buf][wm * 64 + m * 16 + fr][ko]);
#pragma unroll
        for (int n = 0; n < 4; ++n)
            bf[n] = *reinterpret_cast<const s16x8*>(&Bl[buf][wn * 64 + n * 16 + fr][ko]);
#pragma unroll
        for (int m = 0; m < 4; ++m)
#pragma unroll
            for (int n = 0; n < 4; ++n)
                acc[m][n] = mfma16x16x32(af[m], bf[n], acc[m][n]);
    };

    stage(0, 0);
    __syncthreads();
#pragma unroll 1
    for (int t = 0; t < NT; ++t) {
        const int cur = t & 1;
        if (t + 1 < NT) stage(cur ^ 1, (t + 1) * 32);
        compute(cur);
        __syncthreads();
    }

#pragma unroll
    for (int m = 0; m < 4; ++m)
#pragma unroll
        for (int n = 0; n < 4; ++n) {
            const int col = n0 + wn * 64 + n * 16 + fr;
#pragma unroll
            for (int r = 0; r < 4; ++r) {
                const int rt = wm * 64 + m * 16 + fq * 4 + r;
                if (rt < mval)
                    obuf[(size_t)(p0 + rt) * NB + col] = f2bf(acc[m][n][r]);
            }
        }
}

// ---------------- swiglu combine: act = silu(h)*u (expert + shared) ----------------
__global__ __launch_bounds__(256)
void swiglu_kernel(const unsigned short* __restrict__ hexp,
                   const unsigned short* __restrict__ uexp,
                   unsigned short* __restrict__ act,
                   const unsigned short* __restrict__ shh,
                   const unsigned short* __restrict__ shu,
                   unsigned short* __restrict__ shact)
{
    constexpr size_t NE = (size_t)NPAIR * HEXP;   // 4194304
    const size_t i = ((size_t)blockIdx.x * 256 + threadIdx.x) * 8;
    const unsigned short *hp, *up;
    unsigned short* ap;
    size_t j;
    if (i < NE) { hp = hexp; up = uexp; ap = act; j = i; }
    else        { hp = shh;  up = shu;  ap = shact; j = i - NE; }
    const uint4 hv = *reinterpret_cast<const uint4*>(hp + j);
    const uint4 uv = *reinterpret_cast<const uint4*>(up + j);
    const unsigned short* hu = reinterpret_cast<const unsigned short*>(&hv);
    const unsigned short* uu = reinterpret_cast<const unsigned short*>(&uv);
    ushort4 o[2];
    unsigned short* ou = reinterpret_cast<unsigned short*>(o);
#pragma unroll
    for (int k = 0; k < 8; ++k) {
        const float h = bf2f(hu[k]);
        const float u = bf2f(uu[k]);
        ou[k] = f2bf(h / (1.f + __expf(-h)) * u);
    }
    *reinterpret_cast<uint4*>(ap + j) = *reinterpret_cast<const uint4*>(o);
}

// ---------------- down GEMM, m97 shape 128x128: expert(->ypair) + shared(->sdown) --
__global__ __launch_bounds__(256, 3)
void down128_kernel(const unsigned short* __restrict__ act,
                    const unsigned short* __restrict__ shact,
                    const unsigned short* __restrict__ wdb,
                    const unsigned short* __restrict__ sdb,
                    unsigned short* __restrict__ ypair,
                    float* __restrict__ sdown,
                    const int* __restrict__ meta,
                    const float* __restrict__ pair_score)
{
    __shared__ unsigned short Al[2][128][32];
    __shared__ unsigned short Bl[2][128][32];

    const int bid = blockIdx.x;
    const int tid = threadIdx.x;
    const int lane = tid & 63;
    const int wave = tid >> 6;
    const int fr = lane & 15, fq = lane >> 4;
    const int ko = frag_ko(fr, fq);
    const int sub = lane >> 2;
    const int col8 = src_col8(lane);
    const int wm = wave >> 1, wn = wave & 1;
    const f32x4 zero4 = {0.f, 0.f, 0.f, 0.f};

    const bool EXPERT = bid < 16 * NT128;
    int p0, mval, n0, KA;
    const unsigned short *Asrc, *B;
    if (EXPERT) {
        const int tt = bid >> 4;
        if (tt >= meta[M128_NT]) return;
        const int e = meta[M128_TE + tt];
        p0 = meta[M128_TP0 + tt];
        mval = meta[M128_TM + tt];
        n0 = (bid & 15) * 128;
        KA = HEXP;
        Asrc = act;
        B = wdb + (size_t)e * DMODEL * HEXP;
    } else {
        const int idx = bid - 16 * NT128;   // 256 blocks: 16m x 16n
        p0 = (idx >> 4) * 128;
        mval = 128;
        n0 = (idx & 15) * 128;
        KA = HSH;
        Asrc = shact;
        B = sdb;
    }
    const int NT = KA / 32;

    const int arow0 = wave * 32 + sub;
    const unsigned short* asrc0 = Asrc + (size_t)(p0 + arow0) * KA + col8;
    const unsigned short* asrc1 = Asrc + (size_t)(p0 + arow0 + 16) * KA + col8;
    const unsigned short* bsrc0 = B + (size_t)(n0 + arow0) * KA + col8;
    const unsigned short* bsrc1 = B + (size_t)(n0 + arow0 + 16) * KA + col8;

    auto stage = [&](int buf, int k0) {
        gload16(asrc0 + k0, &Al[buf][wave * 32][0]);
        gload16(asrc1 + k0, &Al[buf][wave * 32 + 16][0]);
        gload16(bsrc0 + k0, &Bl[buf][wave * 32][0]);
        gload16(bsrc1 + k0, &Bl[buf][wave * 32 + 16][0]);
    };

    f32x4 acc[4][4];
#pragma unroll
    for (int m = 0; m < 4; ++m)
#pragma unroll
        for (int n = 0; n < 4; ++n) acc[m][n] = zero4;

    auto compute = [&](int buf) {
        s16x8 af[4], bf[4];
#pragma unroll
        for (int m = 0; m < 4; ++m)
            af[m] = *reinterpret_cast<const s16x8*>(&Al[buf][wm * 64 + m * 16 + fr][ko]);
#pragma unroll
        for (int n = 0; n < 4; ++n)
            bf[n] = *reinterpret_cast<const s16x8*>(&Bl[buf][wn * 64 + n * 16 + fr][ko]);
#pragma unroll
        for (int m = 0; m < 4; ++m)
#pragma unroll
            for (int n = 0; n < 4; ++n)
                acc[m][n] = mfma16x16x32(af[m], bf[n], acc[m][n]);
    };

    stage(0, 0);
    __syncthreads();
#pragma unroll 1
    for (int t = 0; t < NT; ++t) {
        const int cur = t & 1;
        if (t + 1 < NT) stage(cur ^ 1, (t + 1) * 32);
        compute(cur);
        __syncthreads();
    }

#pragma unroll
    for (int m = 0; m < 4; ++m)
#pragma unroll
        for (int n = 0; n < 4; ++n) {
            const int col = n0 + wn * 64 + n * 16 + fr;
#pragma unroll
            for (int r = 0; r < 4; ++r) {
                const int rt = wm * 64 + m * 16 + fq * 4 + r;
                if (rt < mval) {
                    if (EXPERT) {
                        const int p = p0 + rt;
                        ypair[(size_t)p * DMODEL + col] = f2bf(acc[m][n][r] * pair_score[p]);
                    } else {
                        sdown[(size_t)(p0 + rt) * DMODEL + col] = acc[m][n][r];
                    }
                }
            }
        }
}

// ---------------- final: out = (sum_k ypair[pos_k])*c0 + sdown*c1 ----------------
__global__ __launch_bounds__(256)
void final_kernel(const unsigned short* __restrict__ ypair,
                  const float* __restrict__ sdown,
                  const float* __restrict__ coef, const int* __restrict__ tok_pos,
                  float* __restrict__ out)
{
    const int row = blockIdx.x;
    const int col = threadIdx.x * 8;
    float acc[8] = {0.f, 0.f, 0.f, 0.f, 0.f, 0.f, 0.f, 0.f};
#pragma unroll
    for (int k = 0; k < 4; ++k) {
        const int pos = tok_pos[row * 4 + k];
        const uint4 v = *reinterpret_cast<const uint4*>(ypair + (size_t)pos * DMODEL + col);
        const unsigned short* u = reinterpret_cast<const unsigned short*>(&v);
#pragma unroll
        for (int j = 0; j < 8; ++j) acc[j] += bf2f(u[j]);
    }
    const float c0 = coef[row * 2 + 0];
    const float c1 = coef[row * 2 + 1];
    const float* sd = sdown + (size_t)row * DMODEL + col;
    const float4 s0 = *reinterpret_cast<const float4*>(sd);
    const float4 s1 = *reinterpret_cast<const float4*>(sd + 4);
    float4 o0, o1;
    o0.x = acc[0] * c0 + s0.x * c1; o0.y = acc[1] * c0 + s0.y * c1;
    o0.z = acc[2] * c0 + s0.z * c1; o0.w = acc[3] * c0 + s0.w * c1;
    o1.x = acc[4] * c0 + s1.x * c1; o1.y = acc[5] * c0 + s1.y * c1;
    o1.z = acc[6] * c0 + s1.z * c1; o1.w = acc[7] * c0 + s1.w * c1;
    float* op = out + (size_t)row * DMODEL + col;
    *reinterpret_cast<float4*>(op) = o0;
    *reinterpret_cast<float4*>(op + 4) = o1;
}

// ---------------- launch ----------------
extern "C" void kernel_launch(void* const* d_in, const int* in_sizes, int n_in,
                              void* d_out, int out_size, void* d_ws, size_t ws_size,
                              hipStream_t stream)
{
    const float* x           = (const float*)d_in[0];
    const float* gate_w      = (const float*)d_in[1];
    const float* expert_bias = (const float*)d_in[2];
    const float* wg          = (const float*)d_in[3];
    const float* wu          = (const float*)d_in[4];
    const float* wd          = (const float*)d_in[5];
    const float* sg          = (const float*)d_in[6];
    const float* su          = (const float*)d_in[7];
    const float* sd          = (const float*)d_in[8];
    const float* coef_w      = (const float*)d_in[9];
    const float* coef_b      = (const float*)d_in[10];
    float* out = (float*)d_out;

    char* ws = (char*)d_ws;
    size_t off = 0;
    auto take = [&](size_t bytes) {
        char* p = ws + off;
        off = (off + bytes + 255) & ~(size_t)255;
        return p;
    };
    int*   inds     = (int*)  take((size_t)S_TOK * 4 * sizeof(int));
    float* scores   = (float*)take((size_t)S_TOK * 4 * sizeof(float));
    float* coefp    = (float*)take((size_t)S_TOK * 2 * sizeof(float));
    int*   meta     = (int*)  take((size_t)META_SIZE * sizeof(int));
    int*   pair_tok = (int*)  take((size_t)NPAIR * sizeof(int));
    float* pair_sc  = (float*)take((size_t)NPAIR * sizeof(float));
    int*   tok_pos  = (int*)  take((size_t)NPAIR * sizeof(int));
    unsigned short* xb    = (unsigned short*)take((size_t)S_TOK * DMODEL * 2);
    unsigned short* act   = (unsigned short*)take((size_t)NPAIR * HEXP * 2);
    unsigned short* hexp  = (unsigned short*)take((size_t)NPAIR * HEXP * 2);
    unsigned short* uexp  = (unsigned short*)take((size_t)NPAIR * HEXP * 2);
    unsigned short* shact = (unsigned short*)take((size_t)S_TOK * HSH * 2);
    unsigned short* shh   = (unsigned short*)take((size_t)S_TOK * HSH * 2);
    unsigned short* shu   = (unsigned short*)take((size_t)S_TOK * HSH * 2);
    unsigned short* ypair = (unsigned short*)take((size_t)NPAIR * DMODEL * 2);  // 33.5MB
    float*          sdown = (float*)take((size_t)S_TOK * DMODEL * 4);           // 16.8MB
    unsigned short* sgb   = (unsigned short*)take((size_t)HSH * DMODEL * 2);
    unsigned short* sub_  = (unsigned short*)take((size_t)HSH * DMODEL * 2);
    unsigned short* sdb   = (unsigned short*)take((size_t)DMODEL * HSH * 2);
    unsigned short* W1    = (unsigned short*)take((size_t)NEXP * DMODEL * HEXP * 2); // 64MB
    unsigned short* W2    = (unsigned short*)take((size_t)NEXP * DMODEL * HEXP * 2); // 64MB
    (void)ws_size; (void)in_sizes; (void)n_in; (void)out_size;

    router_kernel<<<S_TOK, 256, 0, stream>>>(x, gate_w, expert_bias, coef_w, coef_b,
                                             inds, scores, coefp);
    xcast_kernel<<<(S_TOK * DMODEL / 4) / 256, 256, 0, stream>>>(x, xb);
    group_kernel<<<1, 1024, 0, stream>>>(inds, scores, meta, pair_tok, pair_sc, tok_pos);

    // all pre-GEMM weight conversions in ONE dispatch
    tconv_all_kernel<<<17920, 256, 0, stream>>>(wg, wu, sg, su, sd,
                                                W1, W2, sgb, sub_, sdb);

    // gate/up GEMMs at m97 density: expert (768) + shared (256) single-mat tiles
    gu128_kernel<<<8 * NT128 + 256, 256, 0, stream>>>(
        xb, W1, W2, meta, pair_tok, sgb, sub_, hexp, uexp, shh, shu);

    // act = silu(h)*u for expert and shared (6.29M elems, 8/thread)
    swiglu_kernel<<<3072, 256, 0, stream>>>(hexp, uexp, act, shh, shu, shact);

    // wd -> bf16 [E][D][H] into W1 (dead after gu128)
    tconv_wd_kernel<<<NEXP * 256, 256, 0, stream>>>(wd, W1);

    // down GEMMs at m97 density: expert (1536 -> ypair) + shared (256 -> sdown)
    down128_kernel<<<16 * NT128 + 256, 256, 0, stream>>>(
        act, shact, W1, sdb, ypair, sdown, meta, pair_sc);

    // final combine (each out element written exactly once)
    final_kernel<<<S_TOK, 256, 0, stream>>>(ypair, sdown, coefp, tok_pos, out);
}

// Round 15
// 333.593 us; speedup vs baseline: 1.9308x; 1.0457x over previous
//
#include <hip/hip_runtime.h>
#include <hip/hip_bf16.h>
#include <stdint.h>

// ---------------- problem dims (fixed by setup_inputs) ----------------
#define S_TOK   2048   // tokens (B*S)
#define DMODEL  2048   // D
#define HEXP    512    // H per expert
#define NEXP    32     // E
#define HSH     1024   // shared hidden
#define NPAIR   (S_TOK * 4)   // 8192 (token,expert) pairs, top_k=4
#define NT128   96            // sum ceil(cnt_e/128) <= 8192/128 + 32

// meta layout (ints): 128-row tile table
#define M128_NT  0
#define M128_TE  1
#define M128_TP0 (1 + NT128)
#define M128_TM  (1 + 2 * NT128)
#define META_SIZE (1 + 3 * NT128)

typedef short  s16x8 __attribute__((ext_vector_type(8)));
typedef __bf16 b16x8 __attribute__((ext_vector_type(8)));
typedef float  f32x4 __attribute__((ext_vector_type(4)));

__device__ __forceinline__ f32x4 mfma16x16x32(s16x8 a, s16x8 b, f32x4 c) {
    return __builtin_amdgcn_mfma_f32_16x16x32_bf16(
        __builtin_bit_cast(b16x8, a), __builtin_bit_cast(b16x8, b), c, 0, 0, 0);
}

__device__ __forceinline__ unsigned short f2bf(float f) {
    union { float f; unsigned int u; } v; v.f = f;
    unsigned int u = v.u;
    return (unsigned short)((u + 0x7FFFu + ((u >> 16) & 1u)) >> 16);  // RNE
}

__device__ __forceinline__ float bf2f(unsigned short b) {
    union { unsigned int u; float f; } v; v.u = ((unsigned int)b) << 16;
    return v.f;
}

// async global->LDS, 16B per lane. LDS dest is wave-uniform base + lane*16.
__device__ __forceinline__ void gload16(const unsigned short* g, unsigned short* l) {
    __builtin_amdgcn_global_load_lds(
        (const __attribute__((address_space(1))) void*)(uintptr_t)g,
        (__attribute__((address_space(3))) void*)(uintptr_t)l, 16, 0, 0);
}

// ---- LDS bank swizzle for [row][32-short] GEMM tiles (64B rows) ----
// write side: pre-swizzled GLOBAL source granule (gload_lds writes linearly);
// read side XORs fq by the same key(row) = ((row&15)>>1)&3.  [rule #21]
__device__ __forceinline__ int src_col8(int lane) {
    return 8 * ((lane & 3) ^ ((lane >> 3) & 3));
}
__device__ __forceinline__ int frag_ko(int fr, int fq) {
    return 8 * (fq ^ ((fr >> 1) & 3));
}

// ---------------- transpose-convert tile: f32 [K][N] -> bf16 [N][K] ----------------
// LDS [64][84] (168B rows): columnar fill ~4-way; global writes as 2x uint4 (16B).
__device__ __forceinline__ void tconv_tile(const float* __restrict__ s,
                                           unsigned short* __restrict__ d,
                                           const int K, const int N,
                                           const int k0, const int n0,
                                           unsigned short* pool)   // >= 64*84 shorts
{
    auto T = (unsigned short (*)[84])pool;
    const int tid = threadIdx.x;
    const int n4 = (tid & 15) * 4;
    const int kr = tid >> 4;
#pragma unroll
    for (int i = 0; i < 4; ++i) {
        const int k = kr + i * 16;
        const float4 v = *reinterpret_cast<const float4*>(s + (size_t)(k0 + k) * N + n0 + n4);
        T[n4 + 0][k] = f2bf(v.x);
        T[n4 + 1][k] = f2bf(v.y);
        T[n4 + 2][k] = f2bf(v.z);
        T[n4 + 3][k] = f2bf(v.w);
    }
    __syncthreads();
    const int nw = tid >> 2;
    const int kc = (tid & 3) * 16;
    const uint2 a0 = *reinterpret_cast<const uint2*>(&T[nw][kc]);
    const uint2 a1 = *reinterpret_cast<const uint2*>(&T[nw][kc + 4]);
    const uint2 a2 = *reinterpret_cast<const uint2*>(&T[nw][kc + 8]);
    const uint2 a3 = *reinterpret_cast<const uint2*>(&T[nw][kc + 12]);
    uint4 w0, w1;
    w0.x = a0.x; w0.y = a0.y; w0.z = a1.x; w0.w = a1.y;
    w1.x = a2.x; w1.y = a2.y; w1.z = a3.x; w1.w = a3.y;
    unsigned short* o = d + (size_t)(n0 + nw) * K + k0 + kc;   // 16B-aligned
    *reinterpret_cast<uint4*>(o)     = w0;
    *reinterpret_cast<uint4*>(o + 8) = w1;
}

// ---------------- router: logits, sigmoid, biased top-4, coef softmax ----------------
__global__ __launch_bounds__(256)
void router_kernel(const float* __restrict__ x, const float* __restrict__ gate_w,
                   const float* __restrict__ expert_bias,
                   const float* __restrict__ coef_w, const float* __restrict__ coef_b,
                   int* __restrict__ inds, float* __restrict__ scores,
                   float* __restrict__ coefo)
{
    const int t = blockIdx.x;
    const int tid = threadIdx.x;
    const int lane = tid & 63;
    const int wave = tid >> 6;
    const float* xr = x + (size_t)t * DMODEL;

    float xv[32];
#pragma unroll
    for (int j = 0; j < 32; ++j) xv[j] = xr[lane + 64 * j];

    __shared__ float s_logits[NEXP];
    __shared__ float s_coef[2];

    for (int i = 0; i < 8; ++i) {
        const int e = wave * 8 + i;
        const float* wr = gate_w + (size_t)e * DMODEL;
        float p = 0.f;
#pragma unroll
        for (int j = 0; j < 32; ++j) p += xv[j] * wr[lane + 64 * j];
#pragma unroll
        for (int o = 32; o > 0; o >>= 1) p += __shfl_xor(p, o);
        if (lane == 0) s_logits[e] = p;
    }
    if (wave == 0) {
        for (int c = 0; c < 2; ++c) {
            const float* wr = coef_w + (size_t)c * DMODEL;
            float p = 0.f;
#pragma unroll
            for (int j = 0; j < 32; ++j) p += xv[j] * wr[lane + 64 * j];
#pragma unroll
            for (int o = 32; o > 0; o >>= 1) p += __shfl_xor(p, o);
            if (lane == 0) s_coef[c] = p;
        }
    }
    __syncthreads();
    if (tid == 0) {
        float routing[NEXP], biased[NEXP];
        for (int e = 0; e < NEXP; ++e) {
            const float r = 1.f / (1.f + expf(-s_logits[e]));
            routing[e] = r;
            biased[e] = r + expert_bias[e];
        }
        int sel[4]; float sc[4]; float ssum = 0.f;
        for (int k = 0; k < 4; ++k) {
            int best = 0; float bv = -1e30f;
            for (int e = 0; e < NEXP; ++e)
                if (biased[e] > bv) { bv = biased[e]; best = e; }  // strict > = lax.top_k tie rule
            sel[k] = best; sc[k] = routing[best]; ssum += sc[k];
            biased[best] = -1e30f;
        }
        const float inv = 1.f / (ssum + 1e-20f);
        for (int k = 0; k < 4; ++k) {
            inds[t * 4 + k] = sel[k];
            scores[t * 4 + k] = sc[k] * inv;
        }
        const float l0 = s_coef[0] + coef_b[0];
        const float l1 = s_coef[1] + coef_b[1];
        const float m = fmaxf(l0, l1);
        const float e0 = expf(l0 - m), e1 = expf(l1 - m);
        coefo[t * 2 + 0] = e0 / (e0 + e1);
        coefo[t * 2 + 1] = e1 / (e0 + e1);
    }
}

// ---------------- x: f32 -> bf16 ----------------
__global__ __launch_bounds__(256)
void xcast_kernel(const float* __restrict__ x, unsigned short* __restrict__ xb)
{
    const int i = (blockIdx.x * 256 + threadIdx.x) * 4;
    const float4 v = *reinterpret_cast<const float4*>(x + i);
    ushort4 o;
    o.x = f2bf(v.x); o.y = f2bf(v.y); o.z = f2bf(v.z); o.w = f2bf(v.w);
    *reinterpret_cast<ushort4*>(xb + i) = o;
}

// ---------------- upfront tconv: wg, wu, sg, su (sd/wd ride on gu128) --------------
__global__ __launch_bounds__(256)
void tconv_all_kernel(const float* __restrict__ wg, const float* __restrict__ wu,
                      const float* __restrict__ sg, const float* __restrict__ su,
                      unsigned short* __restrict__ W1, unsigned short* __restrict__ W2,
                      unsigned short* __restrict__ sgb, unsigned short* __restrict__ sub_)
{
    __shared__ unsigned short pool[64 * 84];
    const int bid = blockIdx.x;
    if (bid < 8192) {               // wg [E][2048][512] -> W1 [E][512][2048]
        const int e = bid >> 8, t = bid & 255;
        tconv_tile(wg + (size_t)e * DMODEL * HEXP, W1 + (size_t)e * HEXP * DMODEL,
                   DMODEL, HEXP, ((t >> 3) & 31) * 64, (t & 7) * 64, pool);
    } else if (bid < 16384) {       // wu -> W2
        const int e = (bid - 8192) >> 8, t = bid & 255;
        tconv_tile(wu + (size_t)e * DMODEL * HEXP, W2 + (size_t)e * HEXP * DMODEL,
                   DMODEL, HEXP, ((t >> 3) & 31) * 64, (t & 7) * 64, pool);
    } else if (bid < 16896) {       // sg [2048][1024] -> sgb [1024][2048]
        const int t = bid - 16384;
        tconv_tile(sg, sgb, DMODEL, HSH, (t >> 4) * 64, (t & 15) * 64, pool);
    } else {                        // su -> sub_
        const int t = bid - 16896;
        tconv_tile(su, sub_, DMODEL, HSH, (t >> 4) * 64, (t & 15) * 64, pool);
    }
}

// ---------------- grouping: pair lists + 128-row tile table + token->pos map ----
__global__ __launch_bounds__(1024)
void group_kernel(const int* __restrict__ inds, const float* __restrict__ scores,
                  int* __restrict__ meta, int* __restrict__ pair_token,
                  float* __restrict__ pair_score, int* __restrict__ tok_pos)
{
    __shared__ int cnt[NEXP];
    __shared__ int off_s[NEXP];
    __shared__ int cur[NEXP];
    const int tid = threadIdx.x;
    if (tid < NEXP) cnt[tid] = 0;
    __syncthreads();
    for (int i = tid; i < NPAIR; i += 1024) atomicAdd(&cnt[inds[i]], 1);
    __syncthreads();
    if (tid == 0) {
        int run = 0, nt1 = 0;
        for (int e = 0; e < NEXP; ++e) {
            off_s[e] = run;
            const int c = cnt[e];
            for (int m0 = 0; m0 < c; m0 += 128) {
                meta[M128_TE + nt1] = e;
                meta[M128_TP0 + nt1] = run + m0;
                meta[M128_TM + nt1] = (c - m0 < 128) ? (c - m0) : 128;
                ++nt1;
            }
            run += c;
        }
        meta[M128_NT] = nt1;
    }
    __syncthreads();
    if (tid < NEXP) cur[tid] = off_s[tid];
    __syncthreads();
    for (int i = tid; i < NPAIR; i += 1024) {
        const int e = inds[i];
        const int pos = atomicAdd(&cur[e], 1);
        pair_token[pos] = i >> 2;
        pair_score[pos] = scores[i];
        tok_pos[i] = pos;
    }
}

// ---------------- gate/up GEMM 128x128 + passenger tconv(wd -> wdb, sd -> sdb) ----
// bid < 8*NT128            : expert tile (tt=bid>>3; r=bid&7: mat=r>>2, n0=(r&3)*128)
// bid in [8*NT128, +256)   : shared tile
// bid >= 8*NT128+256       : passenger tconv (wd: 8192 tiles, sd: 512 tiles).
//   wdb/sdb are consumed only by down128, which launches after this kernel completes.
__global__ __launch_bounds__(256, 3)
void gu128_kernel(const unsigned short* __restrict__ xb,
                  const unsigned short* __restrict__ W1,
                  const unsigned short* __restrict__ W2,
                  const int* __restrict__ meta, const int* __restrict__ pair_token,
                  const unsigned short* __restrict__ sgb,
                  const unsigned short* __restrict__ sub_,
                  unsigned short* __restrict__ hexp, unsigned short* __restrict__ uexp,
                  unsigned short* __restrict__ shh, unsigned short* __restrict__ shu,
                  const float* __restrict__ wd, unsigned short* __restrict__ wdb,
                  const float* __restrict__ sd, unsigned short* __restrict__ sdb)
{
    constexpr int NT = DMODEL / 32;
    __shared__ unsigned short pool[16384];   // 32 KB (GEMM dbuf or tconv tile)
    auto Al = (unsigned short (*)[128][32])(pool);
    auto Bl = (unsigned short (*)[128][32])(pool + 8192);

    const int bid = blockIdx.x;
    const int tid = threadIdx.x;
    const int lane = tid & 63;
    const int wave = tid >> 6;

    if (bid >= 8 * NT128 + 256) {   // ---- passenger tconv role ----
        const int idx = bid - (8 * NT128 + 256);
        if (idx < 8192) {           // wd [E][512][2048] -> wdb [E][2048][512]
            const int e = idx >> 8, t = idx & 255;
            tconv_tile(wd + (size_t)e * HEXP * DMODEL, wdb + (size_t)e * DMODEL * HEXP,
                       HEXP, DMODEL, (t >> 5) * 64, (t & 31) * 64, pool);
        } else {                    // sd [1024][2048] -> sdb [2048][1024]
            const int t = idx - 8192;
            tconv_tile(sd, sdb, HSH, DMODEL, (t >> 5) * 64, (t & 31) * 64, pool);
        }
        return;
    }

    const int fr = lane & 15, fq = lane >> 4;
    const int ko = frag_ko(fr, fq);
    const int sub = lane >> 2;
    const int col8 = src_col8(lane);
    const int wm = wave >> 1, wn = wave & 1;
    const f32x4 zero4 = {0.f, 0.f, 0.f, 0.f};

    const bool EXPERT = bid < 8 * NT128;
    int p0, mval, n0, NB;
    const unsigned short* B;
    unsigned short* obuf;
    int tok0, tok1;
    const int arow0 = wave * 32 + sub;
    if (EXPERT) {
        const int tt = bid >> 3;
        if (tt >= meta[M128_NT]) return;
        const int e = meta[M128_TE + tt];
        p0 = meta[M128_TP0 + tt];
        mval = meta[M128_TM + tt];
        const int r = bid & 7;
        const int mat = r >> 2;
        n0 = (r & 3) * 128;
        NB = HEXP;
        B = (mat ? W2 : W1) + (size_t)e * HEXP * DMODEL;
        obuf = mat ? uexp : hexp;
        int q0 = p0 + arow0;      if (q0 > NPAIR - 1) q0 = NPAIR - 1;
        int q1 = p0 + arow0 + 16; if (q1 > NPAIR - 1) q1 = NPAIR - 1;
        tok0 = pair_token[q0];
        tok1 = pair_token[q1];
    } else {
        const int idx = bid - 8 * NT128;   // 256 blocks: 16m x 8n x 2mats
        const int mat = idx & 1;
        n0 = ((idx >> 1) & 7) * 128;
        p0 = (idx >> 4) * 128;
        mval = 128;
        NB = HSH;
        B = mat ? sub_ : sgb;
        obuf = mat ? shu : shh;
        tok0 = p0 + arow0;
        tok1 = p0 + arow0 + 16;
    }

    const unsigned short* asrc0 = xb + (size_t)tok0 * DMODEL + col8;
    const unsigned short* asrc1 = xb + (size_t)tok1 * DMODEL + col8;
    const unsigned short* bsrc0 = B + (size_t)(n0 + arow0) * DMODEL + col8;
    const unsigned short* bsrc1 = B + (size_t)(n0 + arow0 + 16) * DMODEL + col8;

    auto stage = [&](int buf, int k0) {
        gload16(asrc0 + k0, &Al[buf][wave * 32][0]);
        gload16(asrc1 + k0, &Al[buf][wave * 32 + 16][0]);
        gload16(bsrc0 + k0, &Bl[buf][wave * 32][0]);
        gload16(bsrc1 + k0, &Bl[buf][wave * 32 + 16][0]);
    };

    f32x4 acc[4][4];
#pragma unroll
    for (int m = 0; m < 4; ++m)
#pragma unroll
        for (int n = 0; n < 4; ++n) acc[m][n] = zero4;

    auto compute = [&](int buf) {
        s16x8 af[4], bf[4];
#pragma unroll
        for (int m = 0; m < 4; ++m)
            af[m] = *reinterpret_cast<const s16x8*>(&Al[buf][wm * 64 + m * 16 + fr][ko]);
#pragma unroll
        for (int n = 0; n < 4; ++n)
            bf[n] = *reinterpret_cast<const s16x8*>(&Bl[buf][wn * 64 + n * 16 + fr][ko]);
#pragma unroll
        for (int m = 0; m < 4; ++m)
#pragma unroll
            for (int n = 0; n < 4; ++n)
                acc[m][n] = mfma16x16x32(af[m], bf[n], acc[m][n]);
    };

    stage(0, 0);
    __syncthreads();
#pragma unroll 1
    for (int t = 0; t < NT; ++t) {
        const int cur = t & 1;
        if (t + 1 < NT) stage(cur ^ 1, (t + 1) * 32);
        compute(cur);
        __syncthreads();
    }

#pragma unroll
    for (int m = 0; m < 4; ++m)
#pragma unroll
        for (int n = 0; n < 4; ++n) {
            const int col = n0 + wn * 64 + n * 16 + fr;
#pragma unroll
            for (int r = 0; r < 4; ++r) {
                const int rt = wm * 64 + m * 16 + fq * 4 + r;
                if (rt < mval)
                    obuf[(size_t)(p0 + rt) * NB + col] = f2bf(acc[m][n][r]);
            }
        }
}

// ---------------- swiglu combine: act = silu(h)*u (expert + shared) ----------------
__global__ __launch_bounds__(256)
void swiglu_kernel(const unsigned short* __restrict__ hexp,
                   const unsigned short* __restrict__ uexp,
                   unsigned short* __restrict__ act,
                   const unsigned short* __restrict__ shh,
                   const unsigned short* __restrict__ shu,
                   unsigned short* __restrict__ shact)
{
    constexpr size_t NE = (size_t)NPAIR * HEXP;   // 4194304
    const size_t i = ((size_t)blockIdx.x * 256 + threadIdx.x) * 8;
    const unsigned short *hp, *up;
    unsigned short* ap;
    size_t j;
    if (i < NE) { hp = hexp; up = uexp; ap = act; j = i; }
    else        { hp = shh;  up = shu;  ap = shact; j = i - NE; }
    const uint4 hv = *reinterpret_cast<const uint4*>(hp + j);
    const uint4 uv = *reinterpret_cast<const uint4*>(up + j);
    const unsigned short* hu = reinterpret_cast<const unsigned short*>(&hv);
    const unsigned short* uu = reinterpret_cast<const unsigned short*>(&uv);
    ushort4 o[2];
    unsigned short* ou = reinterpret_cast<unsigned short*>(o);
#pragma unroll
    for (int k = 0; k < 8; ++k) {
        const float h = bf2f(hu[k]);
        const float u = bf2f(uu[k]);
        ou[k] = f2bf(h / (1.f + __expf(-h)) * u);
    }
    *reinterpret_cast<uint4*>(ap + j) = *reinterpret_cast<const uint4*>(o);
}

// ---------------- down GEMM 128x128: expert(->ypair) + shared(->sdown) -------------
__global__ __launch_bounds__(256, 3)
void down128_kernel(const unsigned short* __restrict__ act,
                    const unsigned short* __restrict__ shact,
                    const unsigned short* __restrict__ wdb,
                    const unsigned short* __restrict__ sdb,
                    unsigned short* __restrict__ ypair,
                    float* __restrict__ sdown,
                    const int* __restrict__ meta,
                    const float* __restrict__ pair_score)
{
    __shared__ unsigned short Al[2][128][32];
    __shared__ unsigned short Bl[2][128][32];

    const int bid = blockIdx.x;
    const int tid = threadIdx.x;
    const int lane = tid & 63;
    const int wave = tid >> 6;
    const int fr = lane & 15, fq = lane >> 4;
    const int ko = frag_ko(fr, fq);
    const int sub = lane >> 2;
    const int col8 = src_col8(lane);
    const int wm = wave >> 1, wn = wave & 1;
    const f32x4 zero4 = {0.f, 0.f, 0.f, 0.f};

    const bool EXPERT = bid < 16 * NT128;
    int p0, mval, n0, KA;
    const unsigned short *Asrc, *B;
    if (EXPERT) {
        const int tt = bid >> 4;
        if (tt >= meta[M128_NT]) return;
        const int e = meta[M128_TE + tt];
        p0 = meta[M128_TP0 + tt];
        mval = meta[M128_TM + tt];
        n0 = (bid & 15) * 128;
        KA = HEXP;
        Asrc = act;
        B = wdb + (size_t)e * DMODEL * HEXP;
    } else {
        const int idx = bid - 16 * NT128;   // 256 blocks: 16m x 16n
        p0 = (idx >> 4) * 128;
        mval = 128;
        n0 = (idx & 15) * 128;
        KA = HSH;
        Asrc = shact;
        B = sdb;
    }
    const int NT = KA / 32;

    const int arow0 = wave * 32 + sub;
    const unsigned short* asrc0 = Asrc + (size_t)(p0 + arow0) * KA + col8;
    const unsigned short* asrc1 = Asrc + (size_t)(p0 + arow0 + 16) * KA + col8;
    const unsigned short* bsrc0 = B + (size_t)(n0 + arow0) * KA + col8;
    const unsigned short* bsrc1 = B + (size_t)(n0 + arow0 + 16) * KA + col8;

    auto stage = [&](int buf, int k0) {
        gload16(asrc0 + k0, &Al[buf][wave * 32][0]);
        gload16(asrc1 + k0, &Al[buf][wave * 32 + 16][0]);
        gload16(bsrc0 + k0, &Bl[buf][wave * 32][0]);
        gload16(bsrc1 + k0, &Bl[buf][wave * 32 + 16][0]);
    };

    f32x4 acc[4][4];
#pragma unroll
    for (int m = 0; m < 4; ++m)
#pragma unroll
        for (int n = 0; n < 4; ++n) acc[m][n] = zero4;

    auto compute = [&](int buf) {
        s16x8 af[4], bf[4];
#pragma unroll
        for (int m = 0; m < 4; ++m)
            af[m] = *reinterpret_cast<const s16x8*>(&Al[buf][wm * 64 + m * 16 + fr][ko]);
#pragma unroll
        for (int n = 0; n < 4; ++n)
            bf[n] = *reinterpret_cast<const s16x8*>(&Bl[buf][wn * 64 + n * 16 + fr][ko]);
#pragma unroll
        for (int m = 0; m < 4; ++m)
#pragma unroll
            for (int n = 0; n < 4; ++n)
                acc[m][n] = mfma16x16x32(af[m], bf[n], acc[m][n]);
    };

    stage(0, 0);
    __syncthreads();
#pragma unroll 1
    for (int t = 0; t < NT; ++t) {
        const int cur = t & 1;
        if (t + 1 < NT) stage(cur ^ 1, (t + 1) * 32);
        compute(cur);
        __syncthreads();
    }

#pragma unroll
    for (int m = 0; m < 4; ++m)
#pragma unroll
        for (int n = 0; n < 4; ++n) {
            const int col = n0 + wn * 64 + n * 16 + fr;
#pragma unroll
            for (int r = 0; r < 4; ++r) {
                const int rt = wm * 64 + m * 16 + fq * 4 + r;
                if (rt < mval) {
                    if (EXPERT) {
                        const int p = p0 + rt;
                        ypair[(size_t)p * DMODEL + col] = f2bf(acc[m][n][r] * pair_score[p]);
                    } else {
                        sdown[(size_t)(p0 + rt) * DMODEL + col] = acc[m][n][r];
                    }
                }
            }
        }
}

// ---------------- final: out = (sum_k ypair[pos_k])*c0 + sdown*c1 ----------------
__global__ __launch_bounds__(256)
void final_kernel(const unsigned short* __restrict__ ypair,
                  const float* __restrict__ sdown,
                  const float* __restrict__ coef, const int* __restrict__ tok_pos,
                  float* __restrict__ out)
{
    const int row = blockIdx.x;
    const int col = threadIdx.x * 8;
    float acc[8] = {0.f, 0.f, 0.f, 0.f, 0.f, 0.f, 0.f, 0.f};
#pragma unroll
    for (int k = 0; k < 4; ++k) {
        const int pos = tok_pos[row * 4 + k];
        const uint4 v = *reinterpret_cast<const uint4*>(ypair + (size_t)pos * DMODEL + col);
        const unsigned short* u = reinterpret_cast<const unsigned short*>(&v);
#pragma unroll
        for (int j = 0; j < 8; ++j) acc[j] += bf2f(u[j]);
    }
    const float c0 = coef[row * 2 + 0];
    const float c1 = coef[row * 2 + 1];
    const float* sd = sdown + (size_t)row * DMODEL + col;
    const float4 s0 = *reinterpret_cast<const float4*>(sd);
    const float4 s1 = *reinterpret_cast<const float4*>(sd + 4);
    float4 o0, o1;
    o0.x = acc[0] * c0 + s0.x * c1; o0.y = acc[1] * c0 + s0.y * c1;
    o0.z = acc[2] * c0 + s0.z * c1; o0.w = acc[3] * c0 + s0.w * c1;
    o1.x = acc[4] * c0 + s1.x * c1; o1.y = acc[5] * c0 + s1.y * c1;
    o1.z = acc[6] * c0 + s1.z * c1; o1.w = acc[7] * c0 + s1.w * c1;
    float* op = out + (size_t)row * DMODEL + col;
    *reinterpret_cast<float4*>(op) = o0;
    *reinterpret_cast<float4*>(op + 4) = o1;
}

// ---------------- launch ----------------
extern "C" void kernel_launch(void* const* d_in, const int* in_sizes, int n_in,
                              void* d_out, int out_size, void* d_ws, size_t ws_size,
                              hipStream_t stream)
{
    const float* x           = (const float*)d_in[0];
    const float* gate_w      = (const float*)d_in[1];
    const float* expert_bias = (const float*)d_in[2];
    const float* wg          = (const float*)d_in[3];
    const float* wu          = (const float*)d_in[4];
    const float* wd          = (const float*)d_in[5];
    const float* sg          = (const float*)d_in[6];
    const float* su          = (const float*)d_in[7];
    const float* sd          = (const float*)d_in[8];
    const float* coef_w      = (const float*)d_in[9];
    const float* coef_b      = (const float*)d_in[10];
    float* out = (float*)d_out;

    char* ws = (char*)d_ws;
    size_t off = 0;
    auto take = [&](size_t bytes) {
        char* p = ws + off;
        off = (off + bytes + 255) & ~(size_t)255;
        return p;
    };
    int*   inds     = (int*)  take((size_t)S_TOK * 4 * sizeof(int));
    float* scores   = (float*)take((size_t)S_TOK * 4 * sizeof(float));
    float* coefp    = (float*)take((size_t)S_TOK * 2 * sizeof(float));
    int*   meta     = (int*)  take((size_t)META_SIZE * sizeof(int));
    int*   pair_tok = (int*)  take((size_t)NPAIR * sizeof(int));
    float* pair_sc  = (float*)take((size_t)NPAIR * sizeof(float));
    int*   tok_pos  = (int*)  take((size_t)NPAIR * sizeof(int));
    unsigned short* xb    = (unsigned short*)take((size_t)S_TOK * DMODEL * 2);
    unsigned short* act   = (unsigned short*)take((size_t)NPAIR * HEXP * 2);
    unsigned short* hexp  = (unsigned short*)take((size_t)NPAIR * HEXP * 2);
    unsigned short* uexp  = (unsigned short*)take((size_t)NPAIR * HEXP * 2);
    unsigned short* shact = (unsigned short*)take((size_t)S_TOK * HSH * 2);
    unsigned short* shh   = (unsigned short*)take((size_t)S_TOK * HSH * 2);
    unsigned short* shu   = (unsigned short*)take((size_t)S_TOK * HSH * 2);
    unsigned short* ypair = (unsigned short*)take((size_t)NPAIR * DMODEL * 2);  // 33.5MB
    float*          sdown = (float*)take((size_t)S_TOK * DMODEL * 4);           // 16.8MB
    unsigned short* sgb   = (unsigned short*)take((size_t)HSH * DMODEL * 2);
    unsigned short* sub_  = (unsigned short*)take((size_t)HSH * DMODEL * 2);
    unsigned short* sdb   = (unsigned short*)take((size_t)DMODEL * HSH * 2);
    unsigned short* W1    = (unsigned short*)take((size_t)NEXP * DMODEL * HEXP * 2); // 67MB
    unsigned short* W2    = (unsigned short*)take((size_t)NEXP * DMODEL * HEXP * 2); // 67MB
    unsigned short* wdb   = (unsigned short*)take((size_t)NEXP * DMODEL * HEXP * 2); // 67MB
    (void)ws_size; (void)in_sizes; (void)n_in; (void)out_size;

    router_kernel<<<S_TOK, 256, 0, stream>>>(x, gate_w, expert_bias, coef_w, coef_b,
                                             inds, scores, coefp);
    xcast_kernel<<<(S_TOK * DMODEL / 4) / 256, 256, 0, stream>>>(x, xb);
    group_kernel<<<1, 1024, 0, stream>>>(inds, scores, meta, pair_tok, pair_sc, tok_pos);

    // wg/wu/sg/su conversions (wd/sd ride on gu128 as passengers)
    tconv_all_kernel<<<17408, 256, 0, stream>>>(wg, wu, sg, su, W1, W2, sgb, sub_);

    // gate/up GEMMs (768 expert + 256 shared) + 8704 passenger tconv blocks
    gu128_kernel<<<8 * NT128 + 256 + 8704, 256, 0, stream>>>(
        xb, W1, W2, meta, pair_tok, sgb, sub_, hexp, uexp, shh, shu,
        wd, wdb, sd, sdb);

    // act = silu(h)*u for expert and shared (6.29M elems, 8/thread)
    swiglu_kernel<<<3072, 256, 0, stream>>>(hexp, uexp, act, shh, shu, shact);

    // down GEMMs: expert (1536 -> ypair) + shared (256 -> sdown)
    down128_kernel<<<16 * NT128 + 256, 256, 0, stream>>>(
        act, shact, wdb, sdb, ypair, sdown, meta, pair_sc);

    // final combine (each out element written exactly once)
    final_kernel<<<S_TOK, 256, 0, stream>>>(ypair, sdown, coefp, tok_pos, out);
}